// Round 9
// baseline (393.658 us; speedup 1.0000x reference)
//
#include <hip/hip_runtime.h>

namespace {

constexpr int THREADS = 256;
constexpr int HdC = 64, WdC = 96, HuC = 128, WuC = 192;

// ======================= shared helpers =======================

__device__ __forceinline__ float gelu_tanh(float x) {
  float z = 0.7978845608028654f * (x + 0.044715f * x * x * x);
  float e = __expf(2.0f * z);
  float t = 1.0f - 2.0f / (e + 1.0f);
  return 0.5f * x * (1.0f + t);
}

__device__ __forceinline__ unsigned short f2bf(float f) {
  unsigned int u = __builtin_bit_cast(unsigned int, f);
  u = (u + 0x7FFFu + ((u >> 16) & 1u)) >> 16;  // RNE
  return (unsigned short)u;
}

__device__ __forceinline__ float bf2f(unsigned short u) {
  unsigned int x = ((unsigned int)u) << 16;
  return __builtin_bit_cast(float, x);
}

// ======================= fp32 fallback path (round-1, verified) =======================

constexpr int CTX_S = 80;
constexpr int KV_S  = 132;
constexpr int XS_S  = 132;
constexpr int XN_S  = 32;
constexpr int OB_S  = 144;

constexpr int SC_ATT = 0;
constexpr int SC_RED = 0;
constexpr int SC_MU  = 768;
constexpr int SC_RS  = 864;
constexpr int SC_NC  = 1152;
constexpr int SC_LG  = 0;

struct alignas(16) Smem {
  float ctxT[128 * CTX_S];
  float kvb[72 * KV_S];
  float xs[32 * XS_S];
  float xnT[128 * XN_S];
  float outb[32 * OB_S];
  float wbuf[32 * 128];
  float scratch[1536];
};
static_assert(sizeof(Smem) <= 160 * 1024, "LDS budget");

__device__ __forceinline__ void stage_w(const float* __restrict__ W, int wstride,
                                        int kc, float* wbuf, int tid) {
#pragma unroll
  for (int p = 0; p < 4; ++p) {
    int e = tid + p * THREADS;
    int r = e >> 5;
    int c4 = (e & 31) << 2;
    const float4 v = *reinterpret_cast<const float4*>(W + (kc * 32 + r) * wstride + c4);
    *reinterpret_cast<float4*>(wbuf + r * 128 + c4) = v;
  }
}

#define FMA_ROW(ac, s, w)                                            \
  {                                                                  \
    (ac)[0] += (s) * (w).x; (ac)[1] += (s) * (w).y;                  \
    (ac)[2] += (s) * (w).z; (ac)[3] += (s) * (w).w;                  \
  }

__device__ __forceinline__ void gemm32(const float* __restrict__ W, int wstride,
                                       const float* AT, float* wbuf, int tid,
                                       float acc[16]) {
  const int row0 = (tid >> 5) << 2;
  const int col0 = (tid & 31) << 2;
#pragma unroll
  for (int i = 0; i < 16; ++i) acc[i] = 0.f;
  for (int kc = 0; kc < 4; ++kc) {
    __syncthreads();
    stage_w(W, wstride, kc, wbuf, tid);
    __syncthreads();
#pragma unroll 4
    for (int cl = 0; cl < 32; ++cl) {
      const int c = (kc << 5) + cl;
      const float4 a = *reinterpret_cast<const float4*>(AT + c * XN_S + row0);
      const float4 w = *reinterpret_cast<const float4*>(wbuf + cl * 128 + col0);
      FMA_ROW(acc + 0, a.x, w);
      FMA_ROW(acc + 4, a.y, w);
      FMA_ROW(acc + 8, a.z, w);
      FMA_ROW(acc + 12, a.w, w);
    }
  }
}

template <bool NC>
__device__ __forceinline__ void gemm96(const float* __restrict__ W, int wstride,
                                       const float* ctxT, float* wbuf, float* kvb,
                                       const float* __restrict__ bias,
                                       const float* nc, int tid) {
  const int rt4 = (tid >> 5) << 2;
  const int col0 = (tid & 31) << 2;
  float acc[48];
#pragma unroll
  for (int i = 0; i < 48; ++i) acc[i] = 0.f;
  for (int kc = 0; kc < 4; ++kc) {
    __syncthreads();
    stage_w(W, wstride, kc, wbuf, tid);
    __syncthreads();
#pragma unroll 2
    for (int cl = 0; cl < 32; ++cl) {
      const int c = (kc << 5) + cl;
      const float4 w = *reinterpret_cast<const float4*>(wbuf + cl * 128 + col0);
      float s = 0.f, t = 0.f;
      if (NC) { s = nc[c]; t = nc[128 + c]; }
      const float* base = ctxT + c * CTX_S;
#pragma unroll
      for (int p = 0; p < 3; ++p) {
        int r0 = p * 32 + rt4;
        if (r0 > 76) r0 = 76;
        float4 a = *reinterpret_cast<const float4*>(base + r0);
        if (NC) {
          a.x = a.x * s + t; a.y = a.y * s + t;
          a.z = a.z * s + t; a.w = a.w * s + t;
        }
        float* ac = acc + p * 16;
        FMA_ROW(ac + 0, a.x, w);
        FMA_ROW(ac + 4, a.y, w);
        FMA_ROW(ac + 8, a.z, w);
        FMA_ROW(ac + 12, a.w, w);
      }
    }
  }
  const float4 bv = *reinterpret_cast<const float4*>(bias + col0);
#pragma unroll
  for (int p = 0; p < 3; ++p) {
    const int r0 = p * 32 + rt4;
    if (r0 < 72) {
#pragma unroll
      for (int i = 0; i < 4; ++i) {
        float4 o;
        o.x = acc[p * 16 + i * 4 + 0] + bv.x;
        o.y = acc[p * 16 + i * 4 + 1] + bv.y;
        o.z = acc[p * 16 + i * 4 + 2] + bv.z;
        o.w = acc[p * 16 + i * 4 + 3] + bv.w;
        *reinterpret_cast<float4*>(kvb + (r0 + i) * KV_S + col0) = o;
      }
    }
  }
}

__device__ __forceinline__ void layernorm_x(const float* xs, float* xnT,
                                            float* scratch, int tid) {
  const int px = tid & 31;
  const int cg = tid >> 5;
  float s1 = 0.f, s2 = 0.f;
#pragma unroll
  for (int i = 0; i < 16; ++i) {
    const float v = xs[px * XS_S + cg * 16 + i];
    s1 += v; s2 += v * v;
  }
  scratch[SC_RED + cg * 96 + px] = s1;
  scratch[SC_RED + cg * 96 + 48 + px] = s2;
  __syncthreads();
  if (tid < 32) {
    float a = 0.f, b = 0.f;
#pragma unroll
    for (int g = 0; g < 8; ++g) {
      a += scratch[SC_RED + g * 96 + tid];
      b += scratch[SC_RED + g * 96 + 48 + tid];
    }
    const float m = a * (1.f / 128.f);
    const float v = b * (1.f / 128.f) - m * m;
    scratch[SC_MU + tid] = m;
    scratch[SC_RS + tid] = rsqrtf(v + 1e-6f);
  }
  __syncthreads();
  const float m = scratch[SC_MU + px];
  const float r = scratch[SC_RS + px];
#pragma unroll
  for (int i = 0; i < 16; ++i) {
    const int c = cg * 16 + i;
    xnT[c * XN_S + px] = (xs[px * XS_S + c] - m) * r;
  }
}

__global__ __launch_bounds__(THREADS, 1) void fused_interp_kernel(
    const float* __restrict__ fm, const float* __restrict__ fmu,
    const float* __restrict__ nc_w, const float* __restrict__ nc_b,
    const float* __restrict__ wq, const float* __restrict__ bq,
    const float* __restrict__ wkv, const float* __restrict__ bkv,
    const float* __restrict__ wo, const float* __restrict__ bo,
    const float* __restrict__ w1, const float* __restrict__ b1,
    const float* __restrict__ w2, const float* __restrict__ b2,
    const float* __restrict__ wqf, const float* __restrict__ bqf,
    const float* __restrict__ wcf, const float* __restrict__ bcf,
    float* __restrict__ out) {
  __shared__ Smem sm;
  const int tid = threadIdx.x;
  const int bx = blockIdx.x;
  const int by = blockIdx.y;
  const int bz = blockIdx.z;
  const int lh0 = by * 2, lw0 = bx * 4;
  const int hu0 = by * 4, wu0 = bx * 8;

#pragma unroll
  for (int p = 0; p < 16; ++p) {
    const int idx = tid + p * THREADS;
    const int c = idx >> 5;
    const int px = idx & 31;
    const int hu = hu0 + (px >> 3);
    const int wu = wu0 + (px & 7);
    sm.xs[px * XS_S + c] = fmu[((bz * 128 + c) * HuC + hu) * WuC + wu];
  }

  for (int pass = 0; pass < 2; ++pass) {
    const int rl = tid >> 2;
    const int sub = tid & 3;
    const int r = pass * 64 + rl;
    const bool act = (r < 72);
    int base = 0;
    if (act) {
      const int lr = r / 9, kk = r % 9;
      const int hdp = lh0 + (lr >> 2);
      const int wdp = lw0 + (lr & 3);
      const int ki = kk / 3, kj = kk % 3;
      int hs = hdp + ki - 1; hs = hs < 0 ? 0 : (hs > HdC - 1 ? HdC - 1 : hs);
      int ws = wdp + kj - 1; ws = ws < 0 ? 0 : (ws > WdC - 1 ? WdC - 1 : ws);
      base = (bz * 128) * HdC * WdC + hs * WdC + ws;
      float s1 = 0.f, s2 = 0.f;
      for (int i = 0; i < 32; ++i) {
        const float v = fm[base + (sub * 32 + i) * (HdC * WdC)];
        s1 += v; s2 += v * v;
      }
      sm.scratch[SC_RED + sub * 64 + rl] = s1;
      sm.scratch[SC_RED + 384 + sub * 64 + rl] = s2;
    }
    __syncthreads();
    if (tid < 64 && pass * 64 + tid < 72) {
      float a = 0.f, b = 0.f;
#pragma unroll
      for (int s = 0; s < 4; ++s) {
        a += sm.scratch[SC_RED + s * 64 + tid];
        b += sm.scratch[SC_RED + 384 + s * 64 + tid];
      }
      const float m = a * (1.f / 128.f);
      const float v = b * (1.f / 128.f) - m * m;
      sm.scratch[SC_MU + pass * 64 + tid] = m;
      sm.scratch[SC_RS + pass * 64 + tid] = rsqrtf(v + 1e-6f);
    }
    __syncthreads();
    if (act) {
      const float m = sm.scratch[SC_MU + r];
      const float rr = sm.scratch[SC_RS + r];
      for (int i = 0; i < 32; ++i) {
        const int c = sub * 32 + i;
        const float v = fm[base + c * (HdC * WdC)];
        sm.ctxT[c * CTX_S + r] = (v - m) * rr;
      }
    }
    __syncthreads();
  }
  if (tid < 128) {
#pragma unroll
    for (int r = 72; r < 80; ++r) sm.ctxT[tid * CTX_S + r] = 0.f;
  }
  __syncthreads();

  const int row0 = (tid >> 5) << 2;
  const int col0 = (tid & 31) << 2;
  float acc[16];

  for (int l = 0; l < 2; ++l) {
    if (tid < 128) sm.scratch[SC_NC + tid] = nc_w[l * 128 + tid];
    else           sm.scratch[SC_NC + tid] = nc_b[l * 128 + (tid - 128)];

    layernorm_x(sm.xs, sm.xnT, sm.scratch, tid);
    gemm32(wq + l * 16384, 128, sm.xnT, sm.wbuf, tid, acc);
    {
      const float4 bv = *reinterpret_cast<const float4*>(bq + l * 128 + col0);
#pragma unroll
      for (int i = 0; i < 4; ++i) {
        float4 o;
        o.x = acc[i * 4 + 0] + bv.x; o.y = acc[i * 4 + 1] + bv.y;
        o.z = acc[i * 4 + 2] + bv.z; o.w = acc[i * 4 + 3] + bv.w;
        *reinterpret_cast<float4*>(sm.outb + (row0 + i) * OB_S + col0) = o;
      }
    }
    gemm96<true>(wkv + l * 32768, 256, sm.ctxT, sm.wbuf, sm.kvb,
                 bkv + l * 256, sm.scratch + SC_NC, tid);
    __syncthreads();
    if (tid < 128) {
      const int px = tid >> 2, h = tid & 3;
      const int lr = (((px >> 3) >> 1) << 2) | ((px & 7) >> 1);
      const float* qrow = sm.outb + px * OB_S + h * 32;
      float4 q[8];
#pragma unroll
      for (int d = 0; d < 8; ++d) q[d] = *reinterpret_cast<const float4*>(qrow + d * 4);
      float lg[9];
      float mx = -1e30f;
#pragma unroll
      for (int kk = 0; kk < 9; ++kk) {
        const float* krow = sm.kvb + (lr * 9 + kk) * KV_S + h * 32;
        float s = 0.f;
#pragma unroll
        for (int d = 0; d < 8; ++d) {
          const float4 kv = *reinterpret_cast<const float4*>(krow + d * 4);
          s += q[d].x * kv.x + q[d].y * kv.y + q[d].z * kv.z + q[d].w * kv.w;
        }
        s *= 0.17677669529663687f;
        lg[kk] = s;
        mx = fmaxf(mx, s);
      }
      float sum = 0.f;
#pragma unroll
      for (int kk = 0; kk < 9; ++kk) { lg[kk] = __expf(lg[kk] - mx); sum += lg[kk]; }
      const float inv = 1.f / sum;
#pragma unroll
      for (int kk = 0; kk < 9; ++kk)
        sm.scratch[SC_ATT + (px * 4 + h) * 9 + kk] = lg[kk] * inv;
    }
    __syncthreads();
    gemm96<true>(wkv + l * 32768 + 128, 256, sm.ctxT, sm.wbuf, sm.kvb,
                 bkv + l * 256 + 128, sm.scratch + SC_NC, tid);
    __syncthreads();
    {
      const int c = tid & 127, pg = tid >> 7;
      const int h = c >> 5;
#pragma unroll 4
      for (int i = 0; i < 16; ++i) {
        const int px = pg * 16 + i;
        const int lr = (((px >> 3) >> 1) << 2) | ((px & 7) >> 1);
        const float* aw = sm.scratch + SC_ATT + (px * 4 + h) * 9;
        float s = 0.f;
#pragma unroll
        for (int kk = 0; kk < 9; ++kk) s += aw[kk] * sm.kvb[(lr * 9 + kk) * KV_S + c];
        sm.xnT[c * XN_S + px] = s;
      }
    }
    gemm32(wo + l * 16384, 128, sm.xnT, sm.wbuf, tid, acc);
    {
      const float4 bv = *reinterpret_cast<const float4*>(bo + l * 128 + col0);
#pragma unroll
      for (int i = 0; i < 4; ++i) {
        float* xr = sm.xs + (row0 + i) * XS_S + col0;
        float4 x = *reinterpret_cast<float4*>(xr);
        x.x += acc[i * 4 + 0] + bv.x; x.y += acc[i * 4 + 1] + bv.y;
        x.z += acc[i * 4 + 2] + bv.z; x.w += acc[i * 4 + 3] + bv.w;
        *reinterpret_cast<float4*>(xr) = x;
      }
    }
    __syncthreads();
    layernorm_x(sm.xs, sm.xnT, sm.scratch, tid);
    float xd[16];
#pragma unroll
    for (int i = 0; i < 16; ++i) xd[i] = 0.f;
    for (int cc = 0; cc < 4; ++cc) {
      gemm32(w1 + l * 65536 + cc * 128, 512, sm.xnT, sm.wbuf, tid, acc);
      {
        const float4 bv = *reinterpret_cast<const float4*>(b1 + l * 512 + cc * 128 + col0);
#pragma unroll
        for (int i = 0; i < 4; ++i) {
          float4 o;
          o.x = gelu_tanh(acc[i * 4 + 0] + bv.x);
          o.y = gelu_tanh(acc[i * 4 + 1] + bv.y);
          o.z = gelu_tanh(acc[i * 4 + 2] + bv.z);
          o.w = gelu_tanh(acc[i * 4 + 3] + bv.w);
          *reinterpret_cast<float4*>(sm.outb + (row0 + i) * OB_S + col0) = o;
        }
      }
      __syncthreads();
      const float* w2c = w2 + l * 65536 + cc * 16384;
      for (int kc = 0; kc < 4; ++kc) {
        __syncthreads();
        stage_w(w2c, 128, kc, sm.wbuf, tid);
        __syncthreads();
#pragma unroll 4
        for (int cl = 0; cl < 32; ++cl) {
          const int c = (kc << 5) + cl;
          const float a0 = sm.outb[(row0 + 0) * OB_S + c];
          const float a1 = sm.outb[(row0 + 1) * OB_S + c];
          const float a2 = sm.outb[(row0 + 2) * OB_S + c];
          const float a3 = sm.outb[(row0 + 3) * OB_S + c];
          const float4 w = *reinterpret_cast<const float4*>(sm.wbuf + cl * 128 + col0);
          FMA_ROW(xd + 0, a0, w);
          FMA_ROW(xd + 4, a1, w);
          FMA_ROW(xd + 8, a2, w);
          FMA_ROW(xd + 12, a3, w);
        }
      }
    }
    {
      const float4 bv = *reinterpret_cast<const float4*>(b2 + l * 128 + col0);
#pragma unroll
      for (int i = 0; i < 4; ++i) {
        float* xr = sm.xs + (row0 + i) * XS_S + col0;
        float4 x = *reinterpret_cast<float4*>(xr);
        x.x += xd[i * 4 + 0] + bv.x; x.y += xd[i * 4 + 1] + bv.y;
        x.z += xd[i * 4 + 2] + bv.z; x.w += xd[i * 4 + 3] + bv.w;
        *reinterpret_cast<float4*>(xr) = x;
      }
    }
    __syncthreads();
  }

  layernorm_x(sm.xs, sm.xnT, sm.scratch, tid);
  gemm32(wqf, 128, sm.xnT, sm.wbuf, tid, acc);
  {
    const float4 bv = *reinterpret_cast<const float4*>(bqf + col0);
#pragma unroll
    for (int i = 0; i < 4; ++i) {
      float4 o;
      o.x = acc[i * 4 + 0] + bv.x; o.y = acc[i * 4 + 1] + bv.y;
      o.z = acc[i * 4 + 2] + bv.z; o.w = acc[i * 4 + 3] + bv.w;
      *reinterpret_cast<float4*>(sm.outb + (row0 + i) * OB_S + col0) = o;
    }
  }
  gemm96<false>(wcf, 128, sm.ctxT, sm.wbuf, sm.kvb, bcf, nullptr, tid);
  __syncthreads();
  {
    const int px = tid >> 3, sub = tid & 7;
    const int lr = (((px >> 3) >> 1) << 2) | ((px & 7) >> 1);
    const float* qrow = sm.outb + px * OB_S;
    {
      const float* crow = sm.kvb + (lr * 9 + sub) * KV_S;
      float s = 0.f;
#pragma unroll 8
      for (int c = 0; c < 128; c += 4) {
        const float4 qv = *reinterpret_cast<const float4*>(qrow + c);
        const float4 cv = *reinterpret_cast<const float4*>(crow + c);
        s += qv.x * cv.x + qv.y * cv.y + qv.z * cv.z + qv.w * cv.w;
      }
      sm.scratch[SC_LG + px * 12 + sub] = s;
    }
    if (sub == 0) {
      const float* crow = sm.kvb + (lr * 9 + 8) * KV_S;
      float s = 0.f;
#pragma unroll 8
      for (int c = 0; c < 128; c += 4) {
        const float4 qv = *reinterpret_cast<const float4*>(qrow + c);
        const float4 cv = *reinterpret_cast<const float4*>(crow + c);
        s += qv.x * cv.x + qv.y * cv.y + qv.z * cv.z + qv.w * cv.w;
      }
      sm.scratch[SC_LG + px * 12 + 8] = s;
    }
  }
  __syncthreads();
  if (tid < 32) {
    const int px = tid;
    const int hu = hu0 + (px >> 3), wu = wu0 + (px & 7);
    float lg[9], mx = -1e30f;
#pragma unroll
    for (int kk = 0; kk < 9; ++kk) {
      lg[kk] = sm.scratch[SC_LG + px * 12 + kk] * 0.08838834764831845f;
      mx = fmaxf(mx, lg[kk]);
    }
    float sum = 0.f;
#pragma unroll
    for (int kk = 0; kk < 9; ++kk) { lg[kk] = __expf(lg[kk] - mx); sum += lg[kk]; }
    const float inv = 1.f / sum;
#pragma unroll
    for (int kk = 0; kk < 9; ++kk)
      out[((bz * 9 + kk) * HuC + hu) * WuC + wu] = lg[kk] * inv;
  }
}

// ======================= MFMA path (v9) =======================
// Round-7 structure (225 us, no spills) squeezed to 52.7 KB LDS via aliasing
// (q/xq live in xn; hb aliases kvb; 72-row buffers with overlapping 5th tile;
// LN partials alias prob scratch) -> 3 blocks/CU, 12 waves/CU, grid = 2 rounds.

constexpr int PANEL = 16384;              // u16 per 128x128 panel, [n][k] layout
constexpr int N_PANELS = 26;
constexpr size_t WS_NEEDED = (size_t)N_PANELS * PANEL * 2 + 2048;
constexpr int CBS = 136;                  // bf16 LDS row stride
constexpr int XTS = 132;                  // fp32 temp stride

constexpr int MSC_ATT = 0;                // 1152: attn probs; also LN partials, patch partials, final logits (time-disjoint)
constexpr int MSC_LN  = 0;                // 256: LN partials (alias of probs region)
constexpr int MSC_ST  = 1152;             // 48: patch stats
constexpr int MSC_N   = 1200;

typedef __attribute__((ext_vector_type(8))) short bf16x8;
typedef __attribute__((ext_vector_type(4))) float f32x4;
typedef __attribute__((ext_vector_type(8))) unsigned short u16x8;

struct alignas(16) SmemM {
  unsigned short ctxn[72 * CBS];    // 19584 B; alias xtmp f32[32*132]=16896
  unsigned short kvb[72 * CBS];     // 19584 B; alias patch f32[24*132]=12672; alias hb in MLP
  unsigned short xn[32 * CBS];      //  8704 B; LN(x) / q / o / xq (time-multiplexed)
  float scratch[MSC_N];             //  4800 B
};
static_assert(sizeof(SmemM) <= 53248, "LDS budget (need 3 blocks/CU)");

__global__ void prep_weights(
    const float* __restrict__ nc_w, const float* __restrict__ nc_b,
    const float* __restrict__ wq, const float* __restrict__ wkv,
    const float* __restrict__ bkv,
    const float* __restrict__ wo, const float* __restrict__ w1,
    const float* __restrict__ w2, const float* __restrict__ wqf,
    const float* __restrict__ wcf,
    unsigned short* __restrict__ wsp, float* __restrict__ wsb) {
  const int b = blockIdx.x;
  const int t = threadIdx.x;
  if (b >= 104) {  // adjusted kv bias: b' = bkv + nc_b @ wkv
    const int l = b - 104;
    float acc = bkv[l * 256 + t];
    for (int k = 0; k < 128; ++k)
      acc += nc_b[l * 128 + k] * wkv[l * 32768 + k * 256 + t];
    wsb[l * 256 + t] = acc;
    return;
  }
  const int pid = b >> 2, qtr = b & 3;
  const float* src = wqf; int N = 128, koff = 0, noff = 0;
  const float* sc = nullptr;
  if (pid < 24) {
    const int l = pid / 12, loc = pid % 12;
    if (loc == 0)      { src = wq + l * 16384;  N = 128; }
    else if (loc == 1) { src = wkv + l * 32768; N = 256; sc = nc_w + l * 128; }
    else if (loc == 2) { src = wkv + l * 32768; N = 256; noff = 128; sc = nc_w + l * 128; }
    else if (loc == 3) { src = wo + l * 16384;  N = 128; }
    else if (loc < 8)  { src = w1 + l * 65536;  N = 512; noff = (loc - 4) * 128; }
    else               { src = w2 + l * 65536;  N = 128; koff = (loc - 8) * 128; }
  } else if (pid == 25) { src = wcf; }
  unsigned short* dst = wsp + pid * PANEL;
#pragma unroll
  for (int p = 0; p < 2; ++p) {
    const int e = t + p * 256;
    const int n = e & 127;
    const int kg = e >> 7;
    const int k0 = qtr * 32 + kg * 8;
    unsigned short tmp[8];
#pragma unroll
    for (int i = 0; i < 8; ++i) {
      const float s = sc ? sc[k0 + i] : 1.f;
      tmp[i] = f2bf(src[(k0 + i + koff) * N + noff + n] * s);
    }
    *reinterpret_cast<u16x8*>(dst + n * 128 + k0) = *reinterpret_cast<u16x8*>(tmp);
  }
}

// load 2 col-tiles x 4 k-slices of B fragments (tiles 2*wave, 2*wave+1)
__device__ __forceinline__ void load_b8(const unsigned short* __restrict__ W,
                                        bf16x8 b[2][4], int nl, int q8, int w2t) {
#pragma unroll
  for (int t = 0; t < 2; ++t)
#pragma unroll
    for (int ks = 0; ks < 4; ++ks)
      b[t][ks] = *reinterpret_cast<const bf16x8*>(
          W + ((w2t + t) * 16 + nl) * 128 + ks * 32 + q8);
}

// 32x128 @ 128x(2 tiles): acc[rt*2+t], both row tiles
__device__ __forceinline__ void mfma32v(const unsigned short* A, const bf16x8 b[2][4],
                                        f32x4 acc[4], int nl, int q8, bool init) {
  if (init) {
#pragma unroll
    for (int i = 0; i < 4; ++i) acc[i] = (f32x4){0.f, 0.f, 0.f, 0.f};
  }
#pragma unroll
  for (int ks = 0; ks < 4; ++ks) {
    const bf16x8 a0 = *reinterpret_cast<const bf16x8*>(A + nl * CBS + ks * 32 + q8);
    const bf16x8 a1 = *reinterpret_cast<const bf16x8*>(A + (16 + nl) * CBS + ks * 32 + q8);
    acc[0] = __builtin_amdgcn_mfma_f32_16x16x32_bf16(a0, b[0][ks], acc[0], 0, 0, 0);
    acc[1] = __builtin_amdgcn_mfma_f32_16x16x32_bf16(a0, b[1][ks], acc[1], 0, 0, 0);
    acc[2] = __builtin_amdgcn_mfma_f32_16x16x32_bf16(a1, b[0][ks], acc[2], 0, 0, 0);
    acc[3] = __builtin_amdgcn_mfma_f32_16x16x32_bf16(a1, b[1][ks], acc[3], 0, 0, 0);
  }
}

// 72x128 @ 128x(2 tiles): 5 row tiles at bases {0,16,32,48,56} (tile 4 overlaps
// tile 3 on rows 56..63 -> duplicate results, stores guarded)
__device__ __forceinline__ void mfma72v(const unsigned short* Ctx, const bf16x8 b[2][4],
                                        f32x4 acc[10], int nl, int q8) {
#pragma unroll
  for (int i = 0; i < 10; ++i) acc[i] = (f32x4){0.f, 0.f, 0.f, 0.f};
#pragma unroll
  for (int ks = 0; ks < 4; ++ks) {
    const bf16x8 b0 = b[0][ks], b1 = b[1][ks];
#pragma unroll
    for (int rt = 0; rt < 5; ++rt) {
      const int rb = (rt < 4) ? rt * 16 : 56;
      const bf16x8 a = *reinterpret_cast<const bf16x8*>(
          Ctx + (rb + nl) * CBS + ks * 32 + q8);
      acc[rt * 2 + 0] = __builtin_amdgcn_mfma_f32_16x16x32_bf16(a, b0, acc[rt * 2 + 0], 0, 0, 0);
      acc[rt * 2 + 1] = __builtin_amdgcn_mfma_f32_16x16x32_bf16(a, b1, acc[rt * 2 + 1], 0, 0, 0);
    }
  }
}

// store 72-row gemm result (+bias per col tile) into kvb
__device__ __forceinline__ void store72(unsigned short* kvb, const f32x4 acc[10],
                                        const float bias[2], int nl, int qm, int w2t) {
#pragma unroll
  for (int t = 0; t < 2; ++t) {
    const int n = (w2t + t) * 16 + nl;
#pragma unroll
    for (int rt = 0; rt < 5; ++rt) {
      const int rb = (rt < 4) ? rt * 16 : 56;
#pragma unroll
      for (int r = 0; r < 4; ++r) {
        const int row = rb + qm + r;
        if (rt < 4 || qm + r >= 8)
          kvb[row * CBS + n] = f2bf(acc[rt * 2 + t][r] + bias[t]);
      }
    }
  }
}

// LN of register-resident x (xr[rt][t][r]) -> xn bf16. 2 barriers.
// (first internal barrier also orders prior readers of xn before overwrite)
__device__ __forceinline__ void ln_x(const float (&xr)[2][2][4], unsigned short* xn,
                                     float* scratch, int wave, int nl, int qm) {
#pragma unroll
  for (int rt = 0; rt < 2; ++rt)
#pragma unroll
    for (int r = 0; r < 4; ++r) {
      float s1 = xr[rt][0][r] + xr[rt][1][r];
      float s2 = xr[rt][0][r] * xr[rt][0][r] + xr[rt][1][r] * xr[rt][1][r];
#pragma unroll
      for (int m = 1; m < 16; m <<= 1) {
        s1 += __shfl_xor(s1, m, 64);
        s2 += __shfl_xor(s2, m, 64);
      }
      if (nl == 0) {
        const int px = rt * 16 + qm + r;
        scratch[MSC_LN + px * 4 + wave] = s1;
        scratch[MSC_LN + 128 + px * 4 + wave] = s2;
      }
    }
  __syncthreads();
#pragma unroll
  for (int rt = 0; rt < 2; ++rt)
#pragma unroll
    for (int r = 0; r < 4; ++r) {
      const int px = rt * 16 + qm + r;
      float a = 0.f, b = 0.f;
#pragma unroll
      for (int w = 0; w < 4; ++w) {
        a += scratch[MSC_LN + px * 4 + w];
        b += scratch[MSC_LN + 128 + px * 4 + w];
      }
      const float m = a * (1.f / 128.f);
      const float v = b * (1.f / 128.f) - m * m;
      const float rs = rsqrtf(v + 1e-6f);
#pragma unroll
      for (int t = 0; t < 2; ++t)
        xn[px * CBS + (wave * 2 + t) * 16 + nl] = f2bf((xr[rt][t][r] - m) * rs);
    }
  __syncthreads();
}

__global__ __launch_bounds__(THREADS, 3) void fused_interp_mfma(
    const float* __restrict__ fm, const float* __restrict__ fmu,
    const float* __restrict__ bq, const float* __restrict__ bo,
    const float* __restrict__ b1, const float* __restrict__ b2,
    const float* __restrict__ bqf, const float* __restrict__ bcf,
    const unsigned short* __restrict__ wsp, const float* __restrict__ wsb,
    float* __restrict__ out) {
  __shared__ SmemM sm;
  const int tid = threadIdx.x;
  const int bx = blockIdx.x, by = blockIdx.y, bz = blockIdx.z;
  const int lh0 = by * 2, lw0 = bx * 4;
  const int hu0 = by * 4, wu0 = bx * 8;

  const int lane = tid & 63;
  const int wave = tid >> 6;            // 0..3
  const int nl = lane & 15;
  const int q8 = (lane >> 4) * 8;
  const int qm = (lane >> 4) * 4;
  const int w2t = wave * 2;             // this wave's 2 col tiles / stripes

  // ---- phase 0a: x tile -> xtmp in ctxn (float2 coalesced), then registers ----
  {
    float* xtmp = reinterpret_cast<float*>(sm.ctxn);
#pragma unroll
    for (int p = 0; p < 8; ++p) {
      const int e = tid + p * THREADS;   // 0..2047
      const int pe = e & 15;
      const int c = e >> 4;
      const int hu = hu0 + (pe >> 2);
      const int wu = wu0 + (pe & 3) * 2;
      const float2 v = *reinterpret_cast<const float2*>(
          &fmu[((bz * 128 + c) * HuC + hu) * WuC + wu]);
      const int px = (pe >> 2) * 8 + (pe & 3) * 2;
      xtmp[px * XTS + c] = v.x;
      xtmp[(px + 1) * XTS + c] = v.y;
    }
  }
  __syncthreads();
  float xr[2][2][4];
  {
    const float* xtmp = reinterpret_cast<const float*>(sm.ctxn);
#pragma unroll
    for (int rt = 0; rt < 2; ++rt)
#pragma unroll
      for (int t = 0; t < 2; ++t)
#pragma unroll
        for (int r = 0; r < 4; ++r)
          xr[rt][t][r] = xtmp[(rt * 16 + qm + r) * XTS + (w2t + t) * 16 + nl];
  }
  __syncthreads();

  // ---- phase 0b: patch (4 x 6 low-res px, edge-clamped) in kvb + context LN -> ctxn ----
  {
    float* patch = reinterpret_cast<float*>(sm.kvb);
#pragma unroll
    for (int p = 0; p < 12; ++p) {
      const int e = tid + p * THREADS;  // 0..3071
      const int c = e / 24;
      const int rem = e - c * 24;
      const int hs_i = rem / 6;
      const int ws_i = rem - hs_i * 6;
      int hd = lh0 - 1 + hs_i; hd = hd < 0 ? 0 : (hd > HdC - 1 ? HdC - 1 : hd);
      int wd = lw0 - 1 + ws_i; wd = wd < 0 ? 0 : (wd > WdC - 1 ? WdC - 1 : wd);
      patch[(hs_i * 6 + ws_i) * XTS + c] = fm[((bz * 128 + c) * HdC + hd) * WdC + wd];
    }
  }
  __syncthreads();
  {
    const float* patch = reinterpret_cast<const float*>(sm.kvb);
    if (tid < 192) {
      const int pp = tid >> 3, part = tid & 7;
      float s1 = 0.f, s2 = 0.f;
#pragma unroll
      for (int i = 0; i < 16; ++i) {
        const float v = patch[pp * XTS + part * 16 + i];
        s1 += v; s2 += v * v;
      }
      sm.scratch[MSC_ATT + tid * 2 + 0] = s1;
      sm.scratch[MSC_ATT + tid * 2 + 1] = s2;
    }
    __syncthreads();
    if (tid < 24) {
      float a = 0.f, b = 0.f;
#pragma unroll
      for (int g = 0; g < 8; ++g) {
        a += sm.scratch[MSC_ATT + (tid * 8 + g) * 2 + 0];
        b += sm.scratch[MSC_ATT + (tid * 8 + g) * 2 + 1];
      }
      const float m = a * (1.f / 128.f);
      const float v = b * (1.f / 128.f) - m * m;
      sm.scratch[MSC_ST + tid * 2 + 0] = m;
      sm.scratch[MSC_ST + tid * 2 + 1] = rsqrtf(v + 1e-6f);
    }
    __syncthreads();
#pragma unroll
    for (int p = 0; p < 5; ++p) {
      const int e = tid + p * THREADS;
      if (e < 1152) {
        const int r = e >> 4, cg = e & 15;
        const int lr = r / 9;
        const int kk = r - lr * 9;
        const int ki = kk / 3, kj = kk - ki * 3;
        const int pp = ((lr >> 2) + ki) * 6 + (lr & 3) + kj;
        const float m = sm.scratch[MSC_ST + pp * 2 + 0];
        const float rs = sm.scratch[MSC_ST + pp * 2 + 1];
        unsigned short tmp[8];
#pragma unroll
        for (int j = 0; j < 8; ++j)
          tmp[j] = f2bf((patch[pp * XTS + cg * 8 + j] - m) * rs);
        *reinterpret_cast<u16x8*>(sm.ctxn + r * CBS + cg * 8) = *reinterpret_cast<u16x8*>(tmp);
      }
    }
  }
  __syncthreads();  // ctxn rows 0..71 ready; patch dead -> kvb free

  f32x4 acc4[4];
  f32x4 acc10[10];
  bf16x8 Ba[2][4], Bb[2][4];   // short-lived; never live across a loop back-edge

  for (int l = 0; l < 2; ++l) {
    const unsigned short* P = wsp + (l * 12) * PANEL;

    // preload biases for this layer (latency hidden by ln_x)
    float kb[2], vb[2], bqr[2], bor[2], b2r[2], b1r[4][2];
#pragma unroll
    for (int t = 0; t < 2; ++t) {
      const int n = (w2t + t) * 16 + nl;
      kb[t] = wsb[l * 256 + n];
      vb[t] = wsb[l * 256 + 128 + n];
      bqr[t] = bq[l * 128 + n];
      bor[t] = bo[l * 128 + n];
      b2r[t] = b2[l * 128 + n];
#pragma unroll
      for (int cc = 0; cc < 4; ++cc) b1r[cc][t] = b1[l * 512 + cc * 128 + n];
    }

    // q/k panels in flight during ln_x
    load_b8(P + 0 * PANEL, Ba, nl, q8, w2t);
    load_b8(P + 1 * PANEL, Bb, nl, q8, w2t);
    ln_x(xr, sm.xn, sm.scratch, wave, nl, qm);

    // q = LN(x) @ wq (kept in acc4); k = ctx_n @ wkv_k + b' -> kvb
    mfma32v(sm.xn, Ba, acc4, nl, q8, true);
    mfma72v(sm.ctxn, Bb, acc10, nl, q8);
    load_b8(P + 2 * PANEL, Ba, nl, q8, w2t);  // v panel, in flight through softmax
    store72(sm.kvb, acc10, kb, nl, qm, w2t);
    __syncthreads();  // k visible; all q/k reads of xn/ctxn done
    // q -> xn (overwrites LN(x), now dead)
#pragma unroll
    for (int rt = 0; rt < 2; ++rt)
#pragma unroll
      for (int t = 0; t < 2; ++t) {
        const int n = (w2t + t) * 16 + nl;
#pragma unroll
        for (int r = 0; r < 4; ++r)
          sm.xn[(rt * 16 + qm + r) * CBS + n] = f2bf(acc4[rt * 2 + t][r] + bqr[t]);
      }
    __syncthreads();  // q visible

    // attention softmax: 256 threads, 2 per (px,h), kk split 5/4; q read from xn
    {
      const int u = tid >> 1, sub = tid & 1;
      const int px = u >> 2, h = u & 3;
      const int lr = (((px >> 3) >> 1) << 2) | ((px & 7) >> 1);
      const unsigned short* qrow = sm.xn + px * CBS + h * 32;
      const int base = sub ? 5 : 0;
      const int cnt = sub ? 4 : 5;
      float mine[5];
#pragma unroll
      for (int i = 0; i < 5; ++i) mine[i] = 0.f;
#pragma unroll
      for (int c8 = 0; c8 < 4; ++c8) {
        const u16x8 qa = *reinterpret_cast<const u16x8*>(qrow + c8 * 8);
        float qaf[8];
#pragma unroll
        for (int j = 0; j < 8; ++j) qaf[j] = bf2f(qa[j]);
#pragma unroll
        for (int i = 0; i < 5; ++i) {
          if (i < cnt) {
            const u16x8 ka = *reinterpret_cast<const u16x8*>(
                sm.kvb + (lr * 9 + base + i) * CBS + h * 32 + c8 * 8);
            float s = 0.f;
#pragma unroll
            for (int j = 0; j < 8; ++j) s += qaf[j] * bf2f(ka[j]);
            mine[i] += s;
          }
        }
      }
#pragma unroll
      for (int i = 0; i < 5; ++i) mine[i] *= 0.17677669529663687f;  // 1/sqrt(32)
      float other[5];
#pragma unroll
      for (int i = 0; i < 5; ++i) other[i] = __shfl_xor(mine[i], 1, 64);
      float lg[9];
#pragma unroll
      for (int j = 0; j < 5; ++j) lg[j] = sub ? other[j] : mine[j];
#pragma unroll
      for (int j = 0; j < 4; ++j) lg[5 + j] = sub ? mine[j] : other[j];
      float mx = -1e30f;
#pragma unroll
      for (int kk = 0; kk < 9; ++kk) mx = fmaxf(mx, lg[kk]);
      float sum = 0.f;
#pragma unroll
      for (int kk = 0; kk < 9; ++kk) { lg[kk] = __expf(lg[kk] - mx); sum += lg[kk]; }
      const float inv = 1.f / sum;
#pragma unroll
      for (int j = 0; j < 5; ++j)
        if (j < cnt) sm.scratch[MSC_ATT + (px * 4 + h) * 9 + base + j] = lg[base + j] * inv;
    }
    __syncthreads();  // probs visible; k and q reads done

    // v = ctx_n @ wkv_v + b' -> kvb (overwrites k)
    mfma72v(sm.ctxn, Ba, acc10, nl, q8);
    load_b8(P + 3 * PANEL, Bb, nl, q8, w2t);  // wo panel, in flight through o-section
    store72(sm.kvb, acc10, vb, nl, qm, w2t);
    __syncthreads();  // v visible

    // o = attn @ v -> xn (overwrites q, dead since softmax)
    {
      const int px = tid >> 3, cg = tid & 7, c0 = cg * 16;
      const int lr = (((px >> 3) >> 1) << 2) | ((px & 7) >> 1);
      const float* aw = sm.scratch + MSC_ATT + (px * 4 + (cg >> 1)) * 9;
      float o[16];
#pragma unroll
      for (int j = 0; j < 16; ++j) o[j] = 0.f;
#pragma unroll
      for (int kk = 0; kk < 9; ++kk) {
        const float a = aw[kk];
        const unsigned short* vrow = sm.kvb + (lr * 9 + kk) * CBS + c0;
        const u16x8 v0 = *reinterpret_cast<const u16x8*>(vrow);
        const u16x8 v1 = *reinterpret_cast<const u16x8*>(vrow + 8);
#pragma unroll
        for (int j = 0; j < 8; ++j) {
          o[j] += a * bf2f(v0[j]);
          o[8 + j] += a * bf2f(v1[j]);
        }
      }
      unsigned short tmp[16];
#pragma unroll
      for (int j = 0; j < 16; ++j) tmp[j] = f2bf(o[j]);
      *reinterpret_cast<u16x8*>(sm.xn + px * CBS + c0) = *reinterpret_cast<u16x8*>(tmp);
      *reinterpret_cast<u16x8*>(sm.xn + px * CBS + c0 + 8) = *reinterpret_cast<u16x8*>(tmp + 8);
    }
    __syncthreads();  // xn(o) visible

    // x += o @ wo + bo
    mfma32v(sm.xn, Bb, acc4, nl, q8, true);
#pragma unroll
    for (int rt = 0; rt < 2; ++rt)
#pragma unroll
      for (int t = 0; t < 2; ++t)
#pragma unroll
        for (int r = 0; r < 4; ++r)
          xr[rt][t][r] += acc4[rt * 2 + t][r] + bor[t];

    // MLP: w1_cc -> Ba, w2_cc -> Bb; gelu hidden lives in kvb (v dead)
    load_b8(P + 4 * PANEL, Ba, nl, q8, w2t);  // w1_0, in flight through ln_x
    ln_x(xr, sm.xn, sm.scratch, wave, nl, qm);  // 1st internal barrier drains wo reads
    f32x4 xd[4];
    for (int cc = 0; cc < 4; ++cc) {
      mfma32v(sm.xn, Ba, acc4, nl, q8, true);
      load_b8(P + (8 + cc) * PANEL, Bb, nl, q8, w2t);  // w2_cc, in flight through gelu
#pragma unroll
      for (int rt = 0; rt < 2; ++rt)
#pragma unroll
        for (int t = 0; t < 2; ++t) {
          const int n = (w2t + t) * 16 + nl;
#pragma unroll
          for (int r = 0; r < 4; ++r)
            sm.kvb[(rt * 16 + qm + r) * CBS + n] =
                f2bf(gelu_tanh(acc4[rt * 2 + t][r] + b1r[cc][t]));
        }
      __syncthreads();  // hidden visible
      if (cc < 3) load_b8(P + (5 + cc) * PANEL, Ba, nl, q8, w2t);  // next w1
      mfma32v(sm.kvb, Bb, xd, nl, q8, cc == 0);
      if (cc < 3) __syncthreads();  // hidden reads done before next overwrite
    }
#pragma unroll
    for (int rt = 0; rt < 2; ++rt)
#pragma unroll
      for (int t = 0; t < 2; ++t)
#pragma unroll
        for (int r = 0; r < 4; ++r)
          xr[rt][t][r] += xd[rt * 2 + t][r] + b2r[t];
  }  // layers

  // ---- final: xq = LN(x)@wqf+bqf ; ctxp = LN(ctx)@wcf+bcf ; softmax over 9 ----
  float bqfr[2], bcfr[2];
#pragma unroll
  for (int t = 0; t < 2; ++t) {
    const int n = (w2t + t) * 16 + nl;
    bqfr[t] = bqf[n];
    bcfr[t] = bcf[n];
  }
  load_b8(wsp + 24 * PANEL, Ba, nl, q8, w2t);
  load_b8(wsp + 25 * PANEL, Bb, nl, q8, w2t);
  ln_x(xr, sm.xn, sm.scratch, wave, nl, qm);
  mfma32v(sm.xn, Ba, acc4, nl, q8, true);   // xq (kept in acc4)
  mfma72v(sm.ctxn, Bb, acc10, nl, q8);      // ctxp
  store72(sm.kvb, acc10, bcfr, nl, qm, w2t);
  __syncthreads();  // ctxp visible; xn reads done
#pragma unroll
  for (int rt = 0; rt < 2; ++rt)
#pragma unroll
    for (int t = 0; t < 2; ++t) {
      const int n = (w2t + t) * 16 + nl;
#pragma unroll
      for (int r = 0; r < 4; ++r)
        sm.xn[(rt * 16 + qm + r) * CBS + n] = f2bf(acc4[rt * 2 + t][r] + bqfr[t]);
    }
  __syncthreads();  // xq visible
  {
    const int px = tid >> 3, sub = tid & 7;
    const int lr = (((px >> 3) >> 1) << 2) | ((px & 7) >> 1);
    const unsigned short* qrow = sm.xn + px * CBS;
#pragma unroll
    for (int which = 0; which < 2; ++which) {
      if (which == 1 && sub != 0) break;
      const int kk = (which == 0) ? sub : 8;
      const unsigned short* crow = sm.kvb + (lr * 9 + kk) * CBS;
      float s = 0.f;
#pragma unroll
      for (int c8 = 0; c8 < 16; ++c8) {
        const u16x8 qa = *reinterpret_cast<const u16x8*>(qrow + c8 * 8);
        const u16x8 ca = *reinterpret_cast<const u16x8*>(crow + c8 * 8);
#pragma unroll
        for (int j = 0; j < 8; ++j) s += bf2f(qa[j]) * bf2f(ca[j]);
      }
      sm.scratch[MSC_ATT + px * 12 + kk] = s;
    }
  }
  __syncthreads();
  if (tid < 32) {
    const int px = tid;
    const int hu = hu0 + (px >> 3), wu = wu0 + (px & 7);
    float lg[9], mx = -1e30f;
#pragma unroll
    for (int kk = 0; kk < 9; ++kk) {
      lg[kk] = sm.scratch[MSC_ATT + px * 12 + kk] * 0.08838834764831845f;
      mx = fmaxf(mx, lg[kk]);
    }
    float sum = 0.f;
#pragma unroll
    for (int kk = 0; kk < 9; ++kk) { lg[kk] = __expf(lg[kk] - mx); sum += lg[kk]; }
    const float inv = 1.f / sum;
#pragma unroll
    for (int kk = 0; kk < 9; ++kk)
      out[((bz * 9 + kk) * HuC + hu) * WuC + wu] = lg[kk] * inv;
  }
}

}  // namespace

extern "C" void kernel_launch(void* const* d_in, const int* in_sizes, int n_in,
                              void* d_out, int out_size, void* d_ws, size_t ws_size,
                              hipStream_t stream) {
  const float* fm   = (const float*)d_in[0];
  const float* fmu  = (const float*)d_in[1];
  const float* nc_w = (const float*)d_in[2];
  const float* nc_b = (const float*)d_in[3];
  const float* wq   = (const float*)d_in[4];
  const float* bq   = (const float*)d_in[5];
  const float* wkv  = (const float*)d_in[6];
  const float* bkv  = (const float*)d_in[7];
  const float* wo   = (const float*)d_in[8];
  const float* bo   = (const float*)d_in[9];
  const float* w1   = (const float*)d_in[10];
  const float* b1   = (const float*)d_in[11];
  const float* w2   = (const float*)d_in[12];
  const float* b2   = (const float*)d_in[13];
  const float* wqf  = (const float*)d_in[14];
  const float* bqf  = (const float*)d_in[15];
  const float* wcf  = (const float*)d_in[16];
  const float* bcf  = (const float*)d_in[17];
  float* out = (float*)d_out;

  dim3 grid(24, 32, 2);  // 4x8-pixel tiles
  if (ws_size >= WS_NEEDED) {
    unsigned short* wsp = (unsigned short*)d_ws;
    float* wsb = (float*)((char*)d_ws + (size_t)N_PANELS * PANEL * 2);
    prep_weights<<<dim3(106), dim3(256), 0, stream>>>(
        nc_w, nc_b, wq, wkv, bkv, wo, w1, w2, wqf, wcf, wsp, wsb);
    fused_interp_mfma<<<grid, dim3(THREADS), 0, stream>>>(
        fm, fmu, bq, bo, b1, b2, bqf, bcf, wsp, wsb, out);
  } else {
    fused_interp_kernel<<<grid, dim3(THREADS), 0, stream>>>(
        fm, fmu, nc_w, nc_b, wq, bq, wkv, bkv, wo, bo, w1, b1, w2, b2,
        wqf, bqf, wcf, bcf, out);
  }
}

// Round 10
// 391.262 us; speedup vs baseline: 1.0061x; 1.0061x over previous
//
#include <hip/hip_runtime.h>

namespace {

constexpr int THREADS = 256;
constexpr int HdC = 64, WdC = 96, HuC = 128, WuC = 192;

// ======================= shared helpers =======================

__device__ __forceinline__ float gelu_tanh(float x) {
  float z = 0.7978845608028654f * (x + 0.044715f * x * x * x);
  float e = __expf(2.0f * z);
  float t = 1.0f - 2.0f / (e + 1.0f);
  return 0.5f * x * (1.0f + t);
}

__device__ __forceinline__ unsigned short f2bf(float f) {
  unsigned int u = __builtin_bit_cast(unsigned int, f);
  u = (u + 0x7FFFu + ((u >> 16) & 1u)) >> 16;  // RNE
  return (unsigned short)u;
}

__device__ __forceinline__ float bf2f(unsigned short u) {
  unsigned int x = ((unsigned int)u) << 16;
  return __builtin_bit_cast(float, x);
}

// ======================= fp32 fallback path (round-1, verified) =======================

constexpr int CTX_S = 80;
constexpr int KV_S  = 132;
constexpr int XS_S  = 132;
constexpr int XN_S  = 32;
constexpr int OB_S  = 144;

constexpr int SC_ATT = 0;
constexpr int SC_RED = 0;
constexpr int SC_MU  = 768;
constexpr int SC_RS  = 864;
constexpr int SC_NC  = 1152;
constexpr int SC_LG  = 0;

struct alignas(16) Smem {
  float ctxT[128 * CTX_S];
  float kvb[72 * KV_S];
  float xs[32 * XS_S];
  float xnT[128 * XN_S];
  float outb[32 * OB_S];
  float wbuf[32 * 128];
  float scratch[1536];
};
static_assert(sizeof(Smem) <= 160 * 1024, "LDS budget");

__device__ __forceinline__ void stage_w(const float* __restrict__ W, int wstride,
                                        int kc, float* wbuf, int tid) {
#pragma unroll
  for (int p = 0; p < 4; ++p) {
    int e = tid + p * THREADS;
    int r = e >> 5;
    int c4 = (e & 31) << 2;
    const float4 v = *reinterpret_cast<const float4*>(W + (kc * 32 + r) * wstride + c4);
    *reinterpret_cast<float4*>(wbuf + r * 128 + c4) = v;
  }
}

#define FMA_ROW(ac, s, w)                                            \
  {                                                                  \
    (ac)[0] += (s) * (w).x; (ac)[1] += (s) * (w).y;                  \
    (ac)[2] += (s) * (w).z; (ac)[3] += (s) * (w).w;                  \
  }

__device__ __forceinline__ void gemm32(const float* __restrict__ W, int wstride,
                                       const float* AT, float* wbuf, int tid,
                                       float acc[16]) {
  const int row0 = (tid >> 5) << 2;
  const int col0 = (tid & 31) << 2;
#pragma unroll
  for (int i = 0; i < 16; ++i) acc[i] = 0.f;
  for (int kc = 0; kc < 4; ++kc) {
    __syncthreads();
    stage_w(W, wstride, kc, wbuf, tid);
    __syncthreads();
#pragma unroll 4
    for (int cl = 0; cl < 32; ++cl) {
      const int c = (kc << 5) + cl;
      const float4 a = *reinterpret_cast<const float4*>(AT + c * XN_S + row0);
      const float4 w = *reinterpret_cast<const float4*>(wbuf + cl * 128 + col0);
      FMA_ROW(acc + 0, a.x, w);
      FMA_ROW(acc + 4, a.y, w);
      FMA_ROW(acc + 8, a.z, w);
      FMA_ROW(acc + 12, a.w, w);
    }
  }
}

template <bool NC>
__device__ __forceinline__ void gemm96(const float* __restrict__ W, int wstride,
                                       const float* ctxT, float* wbuf, float* kvb,
                                       const float* __restrict__ bias,
                                       const float* nc, int tid) {
  const int rt4 = (tid >> 5) << 2;
  const int col0 = (tid & 31) << 2;
  float acc[48];
#pragma unroll
  for (int i = 0; i < 48; ++i) acc[i] = 0.f;
  for (int kc = 0; kc < 4; ++kc) {
    __syncthreads();
    stage_w(W, wstride, kc, wbuf, tid);
    __syncthreads();
#pragma unroll 2
    for (int cl = 0; cl < 32; ++cl) {
      const int c = (kc << 5) + cl;
      const float4 w = *reinterpret_cast<const float4*>(wbuf + cl * 128 + col0);
      float s = 0.f, t = 0.f;
      if (NC) { s = nc[c]; t = nc[128 + c]; }
      const float* base = ctxT + c * CTX_S;
#pragma unroll
      for (int p = 0; p < 3; ++p) {
        int r0 = p * 32 + rt4;
        if (r0 > 76) r0 = 76;
        float4 a = *reinterpret_cast<const float4*>(base + r0);
        if (NC) {
          a.x = a.x * s + t; a.y = a.y * s + t;
          a.z = a.z * s + t; a.w = a.w * s + t;
        }
        float* ac = acc + p * 16;
        FMA_ROW(ac + 0, a.x, w);
        FMA_ROW(ac + 4, a.y, w);
        FMA_ROW(ac + 8, a.z, w);
        FMA_ROW(ac + 12, a.w, w);
      }
    }
  }
  const float4 bv = *reinterpret_cast<const float4*>(bias + col0);
#pragma unroll
  for (int p = 0; p < 3; ++p) {
    const int r0 = p * 32 + rt4;
    if (r0 < 72) {
#pragma unroll
      for (int i = 0; i < 4; ++i) {
        float4 o;
        o.x = acc[p * 16 + i * 4 + 0] + bv.x;
        o.y = acc[p * 16 + i * 4 + 1] + bv.y;
        o.z = acc[p * 16 + i * 4 + 2] + bv.z;
        o.w = acc[p * 16 + i * 4 + 3] + bv.w;
        *reinterpret_cast<float4*>(kvb + (r0 + i) * KV_S + col0) = o;
      }
    }
  }
}

__device__ __forceinline__ void layernorm_x(const float* xs, float* xnT,
                                            float* scratch, int tid) {
  const int px = tid & 31;
  const int cg = tid >> 5;
  float s1 = 0.f, s2 = 0.f;
#pragma unroll
  for (int i = 0; i < 16; ++i) {
    const float v = xs[px * XS_S + cg * 16 + i];
    s1 += v; s2 += v * v;
  }
  scratch[SC_RED + cg * 96 + px] = s1;
  scratch[SC_RED + cg * 96 + 48 + px] = s2;
  __syncthreads();
  if (tid < 32) {
    float a = 0.f, b = 0.f;
#pragma unroll
    for (int g = 0; g < 8; ++g) {
      a += scratch[SC_RED + g * 96 + tid];
      b += scratch[SC_RED + g * 96 + 48 + tid];
    }
    const float m = a * (1.f / 128.f);
    const float v = b * (1.f / 128.f) - m * m;
    scratch[SC_MU + tid] = m;
    scratch[SC_RS + tid] = rsqrtf(v + 1e-6f);
  }
  __syncthreads();
  const float m = scratch[SC_MU + px];
  const float r = scratch[SC_RS + px];
#pragma unroll
  for (int i = 0; i < 16; ++i) {
    const int c = cg * 16 + i;
    xnT[c * XN_S + px] = (xs[px * XS_S + c] - m) * r;
  }
}

__global__ __launch_bounds__(THREADS, 1) void fused_interp_kernel(
    const float* __restrict__ fm, const float* __restrict__ fmu,
    const float* __restrict__ nc_w, const float* __restrict__ nc_b,
    const float* __restrict__ wq, const float* __restrict__ bq,
    const float* __restrict__ wkv, const float* __restrict__ bkv,
    const float* __restrict__ wo, const float* __restrict__ bo,
    const float* __restrict__ w1, const float* __restrict__ b1,
    const float* __restrict__ w2, const float* __restrict__ b2,
    const float* __restrict__ wqf, const float* __restrict__ bqf,
    const float* __restrict__ wcf, const float* __restrict__ bcf,
    float* __restrict__ out) {
  __shared__ Smem sm;
  const int tid = threadIdx.x;
  const int bx = blockIdx.x;
  const int by = blockIdx.y;
  const int bz = blockIdx.z;
  const int lh0 = by * 2, lw0 = bx * 4;
  const int hu0 = by * 4, wu0 = bx * 8;

#pragma unroll
  for (int p = 0; p < 16; ++p) {
    const int idx = tid + p * THREADS;
    const int c = idx >> 5;
    const int px = idx & 31;
    const int hu = hu0 + (px >> 3);
    const int wu = wu0 + (px & 7);
    sm.xs[px * XS_S + c] = fmu[((bz * 128 + c) * HuC + hu) * WuC + wu];
  }

  for (int pass = 0; pass < 2; ++pass) {
    const int rl = tid >> 2;
    const int sub = tid & 3;
    const int r = pass * 64 + rl;
    const bool act = (r < 72);
    int base = 0;
    if (act) {
      const int lr = r / 9, kk = r % 9;
      const int hdp = lh0 + (lr >> 2);
      const int wdp = lw0 + (lr & 3);
      const int ki = kk / 3, kj = kk % 3;
      int hs = hdp + ki - 1; hs = hs < 0 ? 0 : (hs > HdC - 1 ? HdC - 1 : hs);
      int ws = wdp + kj - 1; ws = ws < 0 ? 0 : (ws > WdC - 1 ? WdC - 1 : ws);
      base = (bz * 128) * HdC * WdC + hs * WdC + ws;
      float s1 = 0.f, s2 = 0.f;
      for (int i = 0; i < 32; ++i) {
        const float v = fm[base + (sub * 32 + i) * (HdC * WdC)];
        s1 += v; s2 += v * v;
      }
      sm.scratch[SC_RED + sub * 64 + rl] = s1;
      sm.scratch[SC_RED + 384 + sub * 64 + rl] = s2;
    }
    __syncthreads();
    if (tid < 64 && pass * 64 + tid < 72) {
      float a = 0.f, b = 0.f;
#pragma unroll
      for (int s = 0; s < 4; ++s) {
        a += sm.scratch[SC_RED + s * 64 + tid];
        b += sm.scratch[SC_RED + 384 + s * 64 + tid];
      }
      const float m = a * (1.f / 128.f);
      const float v = b * (1.f / 128.f) - m * m;
      sm.scratch[SC_MU + pass * 64 + tid] = m;
      sm.scratch[SC_RS + pass * 64 + tid] = rsqrtf(v + 1e-6f);
    }
    __syncthreads();
    if (act) {
      const float m = sm.scratch[SC_MU + r];
      const float rr = sm.scratch[SC_RS + r];
      for (int i = 0; i < 32; ++i) {
        const int c = sub * 32 + i;
        const float v = fm[base + c * (HdC * WdC)];
        sm.ctxT[c * CTX_S + r] = (v - m) * rr;
      }
    }
    __syncthreads();
  }
  if (tid < 128) {
#pragma unroll
    for (int r = 72; r < 80; ++r) sm.ctxT[tid * CTX_S + r] = 0.f;
  }
  __syncthreads();

  const int row0 = (tid >> 5) << 2;
  const int col0 = (tid & 31) << 2;
  float acc[16];

  for (int l = 0; l < 2; ++l) {
    if (tid < 128) sm.scratch[SC_NC + tid] = nc_w[l * 128 + tid];
    else           sm.scratch[SC_NC + tid] = nc_b[l * 128 + (tid - 128)];

    layernorm_x(sm.xs, sm.xnT, sm.scratch, tid);
    gemm32(wq + l * 16384, 128, sm.xnT, sm.wbuf, tid, acc);
    {
      const float4 bv = *reinterpret_cast<const float4*>(bq + l * 128 + col0);
#pragma unroll
      for (int i = 0; i < 4; ++i) {
        float4 o;
        o.x = acc[i * 4 + 0] + bv.x; o.y = acc[i * 4 + 1] + bv.y;
        o.z = acc[i * 4 + 2] + bv.z; o.w = acc[i * 4 + 3] + bv.w;
        *reinterpret_cast<float4*>(sm.outb + (row0 + i) * OB_S + col0) = o;
      }
    }
    gemm96<true>(wkv + l * 32768, 256, sm.ctxT, sm.wbuf, sm.kvb,
                 bkv + l * 256, sm.scratch + SC_NC, tid);
    __syncthreads();
    if (tid < 128) {
      const int px = tid >> 2, h = tid & 3;
      const int lr = (((px >> 3) >> 1) << 2) | ((px & 7) >> 1);
      const float* qrow = sm.outb + px * OB_S + h * 32;
      float4 q[8];
#pragma unroll
      for (int d = 0; d < 8; ++d) q[d] = *reinterpret_cast<const float4*>(qrow + d * 4);
      float lg[9];
      float mx = -1e30f;
#pragma unroll
      for (int kk = 0; kk < 9; ++kk) {
        const float* krow = sm.kvb + (lr * 9 + kk) * KV_S + h * 32;
        float s = 0.f;
#pragma unroll
        for (int d = 0; d < 8; ++d) {
          const float4 kv = *reinterpret_cast<const float4*>(krow + d * 4);
          s += q[d].x * kv.x + q[d].y * kv.y + q[d].z * kv.z + q[d].w * kv.w;
        }
        s *= 0.17677669529663687f;
        lg[kk] = s;
        mx = fmaxf(mx, s);
      }
      float sum = 0.f;
#pragma unroll
      for (int kk = 0; kk < 9; ++kk) { lg[kk] = __expf(lg[kk] - mx); sum += lg[kk]; }
      const float inv = 1.f / sum;
#pragma unroll
      for (int kk = 0; kk < 9; ++kk)
        sm.scratch[SC_ATT + (px * 4 + h) * 9 + kk] = lg[kk] * inv;
    }
    __syncthreads();
    gemm96<true>(wkv + l * 32768 + 128, 256, sm.ctxT, sm.wbuf, sm.kvb,
                 bkv + l * 256 + 128, sm.scratch + SC_NC, tid);
    __syncthreads();
    {
      const int c = tid & 127, pg = tid >> 7;
      const int h = c >> 5;
#pragma unroll 4
      for (int i = 0; i < 16; ++i) {
        const int px = pg * 16 + i;
        const int lr = (((px >> 3) >> 1) << 2) | ((px & 7) >> 1);
        const float* aw = sm.scratch + SC_ATT + (px * 4 + h) * 9;
        float s = 0.f;
#pragma unroll
        for (int kk = 0; kk < 9; ++kk) s += aw[kk] * sm.kvb[(lr * 9 + kk) * KV_S + c];
        sm.xnT[c * XN_S + px] = s;
      }
    }
    gemm32(wo + l * 16384, 128, sm.xnT, sm.wbuf, tid, acc);
    {
      const float4 bv = *reinterpret_cast<const float4*>(bo + l * 128 + col0);
#pragma unroll
      for (int i = 0; i < 4; ++i) {
        float* xr = sm.xs + (row0 + i) * XS_S + col0;
        float4 x = *reinterpret_cast<float4*>(xr);
        x.x += acc[i * 4 + 0] + bv.x; x.y += acc[i * 4 + 1] + bv.y;
        x.z += acc[i * 4 + 2] + bv.z; x.w += acc[i * 4 + 3] + bv.w;
        *reinterpret_cast<float4*>(xr) = x;
      }
    }
    __syncthreads();
    layernorm_x(sm.xs, sm.xnT, sm.scratch, tid);
    float xd[16];
#pragma unroll
    for (int i = 0; i < 16; ++i) xd[i] = 0.f;
    for (int cc = 0; cc < 4; ++cc) {
      gemm32(w1 + l * 65536 + cc * 128, 512, sm.xnT, sm.wbuf, tid, acc);
      {
        const float4 bv = *reinterpret_cast<const float4*>(b1 + l * 512 + cc * 128 + col0);
#pragma unroll
        for (int i = 0; i < 4; ++i) {
          float4 o;
          o.x = gelu_tanh(acc[i * 4 + 0] + bv.x);
          o.y = gelu_tanh(acc[i * 4 + 1] + bv.y);
          o.z = gelu_tanh(acc[i * 4 + 2] + bv.z);
          o.w = gelu_tanh(acc[i * 4 + 3] + bv.w);
          *reinterpret_cast<float4*>(sm.outb + (row0 + i) * OB_S + col0) = o;
        }
      }
      __syncthreads();
      const float* w2c = w2 + l * 65536 + cc * 16384;
      for (int kc = 0; kc < 4; ++kc) {
        __syncthreads();
        stage_w(w2c, 128, kc, sm.wbuf, tid);
        __syncthreads();
#pragma unroll 4
        for (int cl = 0; cl < 32; ++cl) {
          const int c = (kc << 5) + cl;
          const float a0 = sm.outb[(row0 + 0) * OB_S + c];
          const float a1 = sm.outb[(row0 + 1) * OB_S + c];
          const float a2 = sm.outb[(row0 + 2) * OB_S + c];
          const float a3 = sm.outb[(row0 + 3) * OB_S + c];
          const float4 w = *reinterpret_cast<const float4*>(sm.wbuf + cl * 128 + col0);
          FMA_ROW(xd + 0, a0, w);
          FMA_ROW(xd + 4, a1, w);
          FMA_ROW(xd + 8, a2, w);
          FMA_ROW(xd + 12, a3, w);
        }
      }
    }
    {
      const float4 bv = *reinterpret_cast<const float4*>(b2 + l * 128 + col0);
#pragma unroll
      for (int i = 0; i < 4; ++i) {
        float* xr = sm.xs + (row0 + i) * XS_S + col0;
        float4 x = *reinterpret_cast<float4*>(xr);
        x.x += xd[i * 4 + 0] + bv.x; x.y += xd[i * 4 + 1] + bv.y;
        x.z += xd[i * 4 + 2] + bv.z; x.w += xd[i * 4 + 3] + bv.w;
        *reinterpret_cast<float4*>(xr) = x;
      }
    }
    __syncthreads();
  }

  layernorm_x(sm.xs, sm.xnT, sm.scratch, tid);
  gemm32(wqf, 128, sm.xnT, sm.wbuf, tid, acc);
  {
    const float4 bv = *reinterpret_cast<const float4*>(bqf + col0);
#pragma unroll
    for (int i = 0; i < 4; ++i) {
      float4 o;
      o.x = acc[i * 4 + 0] + bv.x; o.y = acc[i * 4 + 1] + bv.y;
      o.z = acc[i * 4 + 2] + bv.z; o.w = acc[i * 4 + 3] + bv.w;
      *reinterpret_cast<float4*>(sm.outb + (row0 + i) * OB_S + col0) = o;
    }
  }
  gemm96<false>(wcf, 128, sm.ctxT, sm.wbuf, sm.kvb, bcf, nullptr, tid);
  __syncthreads();
  {
    const int px = tid >> 3, sub = tid & 7;
    const int lr = (((px >> 3) >> 1) << 2) | ((px & 7) >> 1);
    const float* qrow = sm.outb + px * OB_S;
    {
      const float* crow = sm.kvb + (lr * 9 + sub) * KV_S;
      float s = 0.f;
#pragma unroll 8
      for (int c = 0; c < 128; c += 4) {
        const float4 qv = *reinterpret_cast<const float4*>(qrow + c);
        const float4 cv = *reinterpret_cast<const float4*>(crow + c);
        s += qv.x * cv.x + qv.y * cv.y + qv.z * cv.z + qv.w * cv.w;
      }
      sm.scratch[SC_LG + px * 12 + sub] = s;
    }
    if (sub == 0) {
      const float* crow = sm.kvb + (lr * 9 + 8) * KV_S;
      float s = 0.f;
#pragma unroll 8
      for (int c = 0; c < 128; c += 4) {
        const float4 qv = *reinterpret_cast<const float4*>(qrow + c);
        const float4 cv = *reinterpret_cast<const float4*>(crow + c);
        s += qv.x * cv.x + qv.y * cv.y + qv.z * cv.z + qv.w * cv.w;
      }
      sm.scratch[SC_LG + px * 12 + 8] = s;
    }
  }
  __syncthreads();
  if (tid < 32) {
    const int px = tid;
    const int hu = hu0 + (px >> 3), wu = wu0 + (px & 7);
    float lg[9], mx = -1e30f;
#pragma unroll
    for (int kk = 0; kk < 9; ++kk) {
      lg[kk] = sm.scratch[SC_LG + px * 12 + kk] * 0.08838834764831845f;
      mx = fmaxf(mx, lg[kk]);
    }
    float sum = 0.f;
#pragma unroll
    for (int kk = 0; kk < 9; ++kk) { lg[kk] = __expf(lg[kk] - mx); sum += lg[kk]; }
    const float inv = 1.f / sum;
#pragma unroll
    for (int kk = 0; kk < 9; ++kk)
      out[((bz * 9 + kk) * HuC + hu) * WuC + wu] = lg[kk] * inv;
  }
}

// ======================= MFMA path (v10) =======================
// v9 (52.7 KB LDS, 3 blocks/CU) with register peak trimmed below the
// 170-reg/wave budget at 3 waves/SIMD: 72-row GEMM split into two
// compute+store groups (acc peak 40 -> 24 regs); per-cc b1 bias loads.

constexpr int PANEL = 16384;              // u16 per 128x128 panel, [n][k] layout
constexpr int N_PANELS = 26;
constexpr size_t WS_NEEDED = (size_t)N_PANELS * PANEL * 2 + 2048;
constexpr int CBS = 136;                  // bf16 LDS row stride
constexpr int XTS = 132;                  // fp32 temp stride

constexpr int MSC_ATT = 0;                // 1152: attn probs; aliased by LN/patch partials/logits (time-disjoint)
constexpr int MSC_LN  = 0;                // 256: LN partials (alias of probs region)
constexpr int MSC_ST  = 1152;             // 48: patch stats
constexpr int MSC_N   = 1200;

typedef __attribute__((ext_vector_type(8))) short bf16x8;
typedef __attribute__((ext_vector_type(4))) float f32x4;
typedef __attribute__((ext_vector_type(8))) unsigned short u16x8;

struct alignas(16) SmemM {
  unsigned short ctxn[72 * CBS];    // 19584 B; alias xtmp f32[32*132]
  unsigned short kvb[72 * CBS];     // 19584 B; alias patch f32[24*132]; alias hb in MLP
  unsigned short xn[32 * CBS];      //  8704 B; LN(x) / q / o / xq (time-multiplexed)
  float scratch[MSC_N];             //  4800 B
};
static_assert(sizeof(SmemM) <= 53248, "LDS budget (need 3 blocks/CU)");

__global__ void prep_weights(
    const float* __restrict__ nc_w, const float* __restrict__ nc_b,
    const float* __restrict__ wq, const float* __restrict__ wkv,
    const float* __restrict__ bkv,
    const float* __restrict__ wo, const float* __restrict__ w1,
    const float* __restrict__ w2, const float* __restrict__ wqf,
    const float* __restrict__ wcf,
    unsigned short* __restrict__ wsp, float* __restrict__ wsb) {
  const int b = blockIdx.x;
  const int t = threadIdx.x;
  if (b >= 104) {  // adjusted kv bias: b' = bkv + nc_b @ wkv
    const int l = b - 104;
    float acc = bkv[l * 256 + t];
    for (int k = 0; k < 128; ++k)
      acc += nc_b[l * 128 + k] * wkv[l * 32768 + k * 256 + t];
    wsb[l * 256 + t] = acc;
    return;
  }
  const int pid = b >> 2, qtr = b & 3;
  const float* src = wqf; int N = 128, koff = 0, noff = 0;
  const float* sc = nullptr;
  if (pid < 24) {
    const int l = pid / 12, loc = pid % 12;
    if (loc == 0)      { src = wq + l * 16384;  N = 128; }
    else if (loc == 1) { src = wkv + l * 32768; N = 256; sc = nc_w + l * 128; }
    else if (loc == 2) { src = wkv + l * 32768; N = 256; noff = 128; sc = nc_w + l * 128; }
    else if (loc == 3) { src = wo + l * 16384;  N = 128; }
    else if (loc < 8)  { src = w1 + l * 65536;  N = 512; noff = (loc - 4) * 128; }
    else               { src = w2 + l * 65536;  N = 128; koff = (loc - 8) * 128; }
  } else if (pid == 25) { src = wcf; }
  unsigned short* dst = wsp + pid * PANEL;
#pragma unroll
  for (int p = 0; p < 2; ++p) {
    const int e = t + p * 256;
    const int n = e & 127;
    const int kg = e >> 7;
    const int k0 = qtr * 32 + kg * 8;
    unsigned short tmp[8];
#pragma unroll
    for (int i = 0; i < 8; ++i) {
      const float s = sc ? sc[k0 + i] : 1.f;
      tmp[i] = f2bf(src[(k0 + i + koff) * N + noff + n] * s);
    }
    *reinterpret_cast<u16x8*>(dst + n * 128 + k0) = *reinterpret_cast<u16x8*>(tmp);
  }
}

// load 2 col-tiles x 4 k-slices of B fragments (tiles 2*wave, 2*wave+1)
__device__ __forceinline__ void load_b8(const unsigned short* __restrict__ W,
                                        bf16x8 b[2][4], int nl, int q8, int w2t) {
#pragma unroll
  for (int t = 0; t < 2; ++t)
#pragma unroll
    for (int ks = 0; ks < 4; ++ks)
      b[t][ks] = *reinterpret_cast<const bf16x8*>(
          W + ((w2t + t) * 16 + nl) * 128 + ks * 32 + q8);
}

// 32x128 @ 128x(2 tiles): acc[rt*2+t], both row tiles
__device__ __forceinline__ void mfma32v(const unsigned short* A, const bf16x8 b[2][4],
                                        f32x4 acc[4], int nl, int q8, bool init) {
  if (init) {
#pragma unroll
    for (int i = 0; i < 4; ++i) acc[i] = (f32x4){0.f, 0.f, 0.f, 0.f};
  }
#pragma unroll
  for (int ks = 0; ks < 4; ++ks) {
    const bf16x8 a0 = *reinterpret_cast<const bf16x8*>(A + nl * CBS + ks * 32 + q8);
    const bf16x8 a1 = *reinterpret_cast<const bf16x8*>(A + (16 + nl) * CBS + ks * 32 + q8);
    acc[0] = __builtin_amdgcn_mfma_f32_16x16x32_bf16(a0, b[0][ks], acc[0], 0, 0, 0);
    acc[1] = __builtin_amdgcn_mfma_f32_16x16x32_bf16(a0, b[1][ks], acc[1], 0, 0, 0);
    acc[2] = __builtin_amdgcn_mfma_f32_16x16x32_bf16(a1, b[0][ks], acc[2], 0, 0, 0);
    acc[3] = __builtin_amdgcn_mfma_f32_16x16x32_bf16(a1, b[1][ks], acc[3], 0, 0, 0);
  }
}

// 72x128 @ 128x(2 tiles) computed+stored in two groups to cap acc regs at 24.
// Group A: row tiles {0,16,32}; group B: row tiles {48, 56} (56-tile overlaps
// rows 56..63 of the 48-tile; duplicate stores guarded to rows 64..71).
__device__ __forceinline__ void gemm72_store(const unsigned short* Ctx,
                                             const bf16x8 b[2][4],
                                             unsigned short* kvb,
                                             const float bias[2],
                                             int nl, int q8, int qm, int w2t) {
  {
    f32x4 acc[6];
#pragma unroll
    for (int i = 0; i < 6; ++i) acc[i] = (f32x4){0.f, 0.f, 0.f, 0.f};
#pragma unroll
    for (int ks = 0; ks < 4; ++ks) {
      const bf16x8 b0 = b[0][ks], b1v = b[1][ks];
#pragma unroll
      for (int rt = 0; rt < 3; ++rt) {
        const bf16x8 a = *reinterpret_cast<const bf16x8*>(
            Ctx + (rt * 16 + nl) * CBS + ks * 32 + q8);
        acc[rt * 2 + 0] = __builtin_amdgcn_mfma_f32_16x16x32_bf16(a, b0, acc[rt * 2 + 0], 0, 0, 0);
        acc[rt * 2 + 1] = __builtin_amdgcn_mfma_f32_16x16x32_bf16(a, b1v, acc[rt * 2 + 1], 0, 0, 0);
      }
    }
#pragma unroll
    for (int t = 0; t < 2; ++t) {
      const int n = (w2t + t) * 16 + nl;
#pragma unroll
      for (int rt = 0; rt < 3; ++rt)
#pragma unroll
        for (int r = 0; r < 4; ++r)
          kvb[(rt * 16 + qm + r) * CBS + n] = f2bf(acc[rt * 2 + t][r] + bias[t]);
    }
  }
  {
    f32x4 acc[4];
#pragma unroll
    for (int i = 0; i < 4; ++i) acc[i] = (f32x4){0.f, 0.f, 0.f, 0.f};
#pragma unroll
    for (int ks = 0; ks < 4; ++ks) {
      const bf16x8 b0 = b[0][ks], b1v = b[1][ks];
      const bf16x8 a0 = *reinterpret_cast<const bf16x8*>(Ctx + (48 + nl) * CBS + ks * 32 + q8);
      const bf16x8 a1 = *reinterpret_cast<const bf16x8*>(Ctx + (56 + nl) * CBS + ks * 32 + q8);
      acc[0] = __builtin_amdgcn_mfma_f32_16x16x32_bf16(a0, b0, acc[0], 0, 0, 0);
      acc[1] = __builtin_amdgcn_mfma_f32_16x16x32_bf16(a0, b1v, acc[1], 0, 0, 0);
      acc[2] = __builtin_amdgcn_mfma_f32_16x16x32_bf16(a1, b0, acc[2], 0, 0, 0);
      acc[3] = __builtin_amdgcn_mfma_f32_16x16x32_bf16(a1, b1v, acc[3], 0, 0, 0);
    }
#pragma unroll
    for (int t = 0; t < 2; ++t) {
      const int n = (w2t + t) * 16 + nl;
#pragma unroll
      for (int r = 0; r < 4; ++r) {
        kvb[(48 + qm + r) * CBS + n] = f2bf(acc[0 + t][r] + bias[t]);
        if (qm + r >= 8)
          kvb[(56 + qm + r) * CBS + n] = f2bf(acc[2 + t][r] + bias[t]);
      }
    }
  }
}

// LN of register-resident x (xr[rt][t][r]) -> xn bf16. 2 barriers.
__device__ __forceinline__ void ln_x(const float (&xr)[2][2][4], unsigned short* xn,
                                     float* scratch, int wave, int nl, int qm) {
#pragma unroll
  for (int rt = 0; rt < 2; ++rt)
#pragma unroll
    for (int r = 0; r < 4; ++r) {
      float s1 = xr[rt][0][r] + xr[rt][1][r];
      float s2 = xr[rt][0][r] * xr[rt][0][r] + xr[rt][1][r] * xr[rt][1][r];
#pragma unroll
      for (int m = 1; m < 16; m <<= 1) {
        s1 += __shfl_xor(s1, m, 64);
        s2 += __shfl_xor(s2, m, 64);
      }
      if (nl == 0) {
        const int px = rt * 16 + qm + r;
        scratch[MSC_LN + px * 4 + wave] = s1;
        scratch[MSC_LN + 128 + px * 4 + wave] = s2;
      }
    }
  __syncthreads();
#pragma unroll
  for (int rt = 0; rt < 2; ++rt)
#pragma unroll
    for (int r = 0; r < 4; ++r) {
      const int px = rt * 16 + qm + r;
      float a = 0.f, b = 0.f;
#pragma unroll
      for (int w = 0; w < 4; ++w) {
        a += scratch[MSC_LN + px * 4 + w];
        b += scratch[MSC_LN + 128 + px * 4 + w];
      }
      const float m = a * (1.f / 128.f);
      const float v = b * (1.f / 128.f) - m * m;
      const float rs = rsqrtf(v + 1e-6f);
#pragma unroll
      for (int t = 0; t < 2; ++t)
        xn[px * CBS + (wave * 2 + t) * 16 + nl] = f2bf((xr[rt][t][r] - m) * rs);
    }
  __syncthreads();
}

__global__ __launch_bounds__(THREADS, 3) void fused_interp_mfma(
    const float* __restrict__ fm, const float* __restrict__ fmu,
    const float* __restrict__ bq, const float* __restrict__ bo,
    const float* __restrict__ b1, const float* __restrict__ b2,
    const float* __restrict__ bqf, const float* __restrict__ bcf,
    const unsigned short* __restrict__ wsp, const float* __restrict__ wsb,
    float* __restrict__ out) {
  __shared__ SmemM sm;
  const int tid = threadIdx.x;
  const int bx = blockIdx.x, by = blockIdx.y, bz = blockIdx.z;
  const int lh0 = by * 2, lw0 = bx * 4;
  const int hu0 = by * 4, wu0 = bx * 8;

  const int lane = tid & 63;
  const int wave = tid >> 6;            // 0..3
  const int nl = lane & 15;
  const int q8 = (lane >> 4) * 8;
  const int qm = (lane >> 4) * 4;
  const int w2t = wave * 2;             // this wave's 2 col tiles / stripes

  // ---- phase 0a: x tile -> xtmp in ctxn (float2 coalesced), then registers ----
  {
    float* xtmp = reinterpret_cast<float*>(sm.ctxn);
#pragma unroll
    for (int p = 0; p < 8; ++p) {
      const int e = tid + p * THREADS;   // 0..2047
      const int pe = e & 15;
      const int c = e >> 4;
      const int hu = hu0 + (pe >> 2);
      const int wu = wu0 + (pe & 3) * 2;
      const float2 v = *reinterpret_cast<const float2*>(
          &fmu[((bz * 128 + c) * HuC + hu) * WuC + wu]);
      const int px = (pe >> 2) * 8 + (pe & 3) * 2;
      xtmp[px * XTS + c] = v.x;
      xtmp[(px + 1) * XTS + c] = v.y;
    }
  }
  __syncthreads();
  float xr[2][2][4];
  {
    const float* xtmp = reinterpret_cast<const float*>(sm.ctxn);
#pragma unroll
    for (int rt = 0; rt < 2; ++rt)
#pragma unroll
      for (int t = 0; t < 2; ++t)
#pragma unroll
        for (int r = 0; r < 4; ++r)
          xr[rt][t][r] = xtmp[(rt * 16 + qm + r) * XTS + (w2t + t) * 16 + nl];
  }
  __syncthreads();

  // ---- phase 0b: patch (4 x 6 low-res px, edge-clamped) in kvb + context LN -> ctxn ----
  {
    float* patch = reinterpret_cast<float*>(sm.kvb);
#pragma unroll
    for (int p = 0; p < 12; ++p) {
      const int e = tid + p * THREADS;  // 0..3071
      const int c = e / 24;
      const int rem = e - c * 24;
      const int hs_i = rem / 6;
      const int ws_i = rem - hs_i * 6;
      int hd = lh0 - 1 + hs_i; hd = hd < 0 ? 0 : (hd > HdC - 1 ? HdC - 1 : hd);
      int wd = lw0 - 1 + ws_i; wd = wd < 0 ? 0 : (wd > WdC - 1 ? WdC - 1 : wd);
      patch[(hs_i * 6 + ws_i) * XTS + c] = fm[((bz * 128 + c) * HdC + hd) * WdC + wd];
    }
  }
  __syncthreads();
  {
    const float* patch = reinterpret_cast<const float*>(sm.kvb);
    if (tid < 192) {
      const int pp = tid >> 3, part = tid & 7;
      float s1 = 0.f, s2 = 0.f;
#pragma unroll
      for (int i = 0; i < 16; ++i) {
        const float v = patch[pp * XTS + part * 16 + i];
        s1 += v; s2 += v * v;
      }
      sm.scratch[MSC_ATT + tid * 2 + 0] = s1;
      sm.scratch[MSC_ATT + tid * 2 + 1] = s2;
    }
    __syncthreads();
    if (tid < 24) {
      float a = 0.f, b = 0.f;
#pragma unroll
      for (int g = 0; g < 8; ++g) {
        a += sm.scratch[MSC_ATT + (tid * 8 + g) * 2 + 0];
        b += sm.scratch[MSC_ATT + (tid * 8 + g) * 2 + 1];
      }
      const float m = a * (1.f / 128.f);
      const float v = b * (1.f / 128.f) - m * m;
      sm.scratch[MSC_ST + tid * 2 + 0] = m;
      sm.scratch[MSC_ST + tid * 2 + 1] = rsqrtf(v + 1e-6f);
    }
    __syncthreads();
#pragma unroll
    for (int p = 0; p < 5; ++p) {
      const int e = tid + p * THREADS;
      if (e < 1152) {
        const int r = e >> 4, cg = e & 15;
        const int lr = r / 9;
        const int kk = r - lr * 9;
        const int ki = kk / 3, kj = kk - ki * 3;
        const int pp = ((lr >> 2) + ki) * 6 + (lr & 3) + kj;
        const float m = sm.scratch[MSC_ST + pp * 2 + 0];
        const float rs = sm.scratch[MSC_ST + pp * 2 + 1];
        unsigned short tmp[8];
#pragma unroll
        for (int j = 0; j < 8; ++j)
          tmp[j] = f2bf((patch[pp * XTS + cg * 8 + j] - m) * rs);
        *reinterpret_cast<u16x8*>(sm.ctxn + r * CBS + cg * 8) = *reinterpret_cast<u16x8*>(tmp);
      }
    }
  }
  __syncthreads();  // ctxn rows 0..71 ready; patch dead -> kvb free

  f32x4 acc4[4];
  bf16x8 Ba[2][4], Bb[2][4];   // short-lived; never live across a loop back-edge

  for (int l = 0; l < 2; ++l) {
    const unsigned short* P = wsp + (l * 12) * PANEL;

    // preload biases for this layer (b1 loaded per-cc inside the MLP loop)
    float kb[2], vb[2], bqr[2], bor[2], b2r[2];
#pragma unroll
    for (int t = 0; t < 2; ++t) {
      const int n = (w2t + t) * 16 + nl;
      kb[t] = wsb[l * 256 + n];
      vb[t] = wsb[l * 256 + 128 + n];
      bqr[t] = bq[l * 128 + n];
      bor[t] = bo[l * 128 + n];
      b2r[t] = b2[l * 128 + n];
    }

    // q/k panels in flight during ln_x
    load_b8(P + 0 * PANEL, Ba, nl, q8, w2t);
    load_b8(P + 1 * PANEL, Bb, nl, q8, w2t);
    ln_x(xr, sm.xn, sm.scratch, wave, nl, qm);

    // q = LN(x) @ wq (kept in acc4); then Ba <- v panel (in flight through k/softmax)
    mfma32v(sm.xn, Ba, acc4, nl, q8, true);
    load_b8(P + 2 * PANEL, Ba, nl, q8, w2t);
    // k = ctx_n @ wkv_k + b' -> kvb (split compute+store, acc peak 24 regs)
    gemm72_store(sm.ctxn, Bb, sm.kvb, kb, nl, q8, qm, w2t);
    __syncthreads();  // k visible; all q/k reads of xn/ctxn done
    // q -> xn (overwrites LN(x), now dead)
#pragma unroll
    for (int rt = 0; rt < 2; ++rt)
#pragma unroll
      for (int t = 0; t < 2; ++t) {
        const int n = (w2t + t) * 16 + nl;
#pragma unroll
        for (int r = 0; r < 4; ++r)
          sm.xn[(rt * 16 + qm + r) * CBS + n] = f2bf(acc4[rt * 2 + t][r] + bqr[t]);
      }
    __syncthreads();  // q visible

    // attention softmax: 256 threads, 2 per (px,h), kk split 5/4; q read from xn
    {
      const int u = tid >> 1, sub = tid & 1;
      const int px = u >> 2, h = u & 3;
      const int lr = (((px >> 3) >> 1) << 2) | ((px & 7) >> 1);
      const unsigned short* qrow = sm.xn + px * CBS + h * 32;
      const int base = sub ? 5 : 0;
      const int cnt = sub ? 4 : 5;
      float mine[5];
#pragma unroll
      for (int i = 0; i < 5; ++i) mine[i] = 0.f;
#pragma unroll
      for (int c8 = 0; c8 < 4; ++c8) {
        const u16x8 qa = *reinterpret_cast<const u16x8*>(qrow + c8 * 8);
        float qaf[8];
#pragma unroll
        for (int j = 0; j < 8; ++j) qaf[j] = bf2f(qa[j]);
#pragma unroll
        for (int i = 0; i < 5; ++i) {
          if (i < cnt) {
            const u16x8 ka = *reinterpret_cast<const u16x8*>(
                sm.kvb + (lr * 9 + base + i) * CBS + h * 32 + c8 * 8);
            float s = 0.f;
#pragma unroll
            for (int j = 0; j < 8; ++j) s += qaf[j] * bf2f(ka[j]);
            mine[i] += s;
          }
        }
      }
#pragma unroll
      for (int i = 0; i < 5; ++i) mine[i] *= 0.17677669529663687f;  // 1/sqrt(32)
      float other[5];
#pragma unroll
      for (int i = 0; i < 5; ++i) other[i] = __shfl_xor(mine[i], 1, 64);
      float lg[9];
#pragma unroll
      for (int j = 0; j < 5; ++j) lg[j] = sub ? other[j] : mine[j];
#pragma unroll
      for (int j = 0; j < 4; ++j) lg[5 + j] = sub ? mine[j] : other[j];
      float mx = -1e30f;
#pragma unroll
      for (int kk = 0; kk < 9; ++kk) mx = fmaxf(mx, lg[kk]);
      float sum = 0.f;
#pragma unroll
      for (int kk = 0; kk < 9; ++kk) { lg[kk] = __expf(lg[kk] - mx); sum += lg[kk]; }
      const float inv = 1.f / sum;
#pragma unroll
      for (int j = 0; j < 5; ++j)
        if (j < cnt) sm.scratch[MSC_ATT + (px * 4 + h) * 9 + base + j] = lg[base + j] * inv;
    }
    __syncthreads();  // probs visible; k and q reads done

    // v = ctx_n @ wkv_v + b' -> kvb (overwrites k); Bb <- wo (in flight through o-section)
    load_b8(P + 3 * PANEL, Bb, nl, q8, w2t);
    gemm72_store(sm.ctxn, Ba, sm.kvb, vb, nl, q8, qm, w2t);
    __syncthreads();  // v visible

    // o = attn @ v -> xn (overwrites q, dead since softmax)
    {
      const int px = tid >> 3, cg = tid & 7, c0 = cg * 16;
      const int lr = (((px >> 3) >> 1) << 2) | ((px & 7) >> 1);
      const float* aw = sm.scratch + MSC_ATT + (px * 4 + (cg >> 1)) * 9;
      float o[16];
#pragma unroll
      for (int j = 0; j < 16; ++j) o[j] = 0.f;
#pragma unroll
      for (int kk = 0; kk < 9; ++kk) {
        const float a = aw[kk];
        const unsigned short* vrow = sm.kvb + (lr * 9 + kk) * CBS + c0;
        const u16x8 v0 = *reinterpret_cast<const u16x8*>(vrow);
        const u16x8 v1 = *reinterpret_cast<const u16x8*>(vrow + 8);
#pragma unroll
        for (int j = 0; j < 8; ++j) {
          o[j] += a * bf2f(v0[j]);
          o[8 + j] += a * bf2f(v1[j]);
        }
      }
      unsigned short tmp[16];
#pragma unroll
      for (int j = 0; j < 16; ++j) tmp[j] = f2bf(o[j]);
      *reinterpret_cast<u16x8*>(sm.xn + px * CBS + c0) = *reinterpret_cast<u16x8*>(tmp);
      *reinterpret_cast<u16x8*>(sm.xn + px * CBS + c0 + 8) = *reinterpret_cast<u16x8*>(tmp + 8);
    }
    __syncthreads();  // xn(o) visible

    // x += o @ wo + bo
    mfma32v(sm.xn, Bb, acc4, nl, q8, true);
#pragma unroll
    for (int rt = 0; rt < 2; ++rt)
#pragma unroll
      for (int t = 0; t < 2; ++t)
#pragma unroll
        for (int r = 0; r < 4; ++r)
          xr[rt][t][r] += acc4[rt * 2 + t][r] + bor[t];

    // MLP: w1_cc -> Ba, w2_cc -> Bb; gelu hidden lives in kvb (v dead)
    load_b8(P + 4 * PANEL, Ba, nl, q8, w2t);  // w1_0, in flight through ln_x
    ln_x(xr, sm.xn, sm.scratch, wave, nl, qm);  // 1st internal barrier drains wo reads
    f32x4 xd[4];
    for (int cc = 0; cc < 4; ++cc) {
      float b1c[2];
#pragma unroll
      for (int t = 0; t < 2; ++t)
        b1c[t] = b1[l * 512 + cc * 128 + (w2t + t) * 16 + nl];
      mfma32v(sm.xn, Ba, acc4, nl, q8, true);
      load_b8(P + (8 + cc) * PANEL, Bb, nl, q8, w2t);  // w2_cc, in flight through gelu
#pragma unroll
      for (int rt = 0; rt < 2; ++rt)
#pragma unroll
        for (int t = 0; t < 2; ++t) {
          const int n = (w2t + t) * 16 + nl;
#pragma unroll
          for (int r = 0; r < 4; ++r)
            sm.kvb[(rt * 16 + qm + r) * CBS + n] =
                f2bf(gelu_tanh(acc4[rt * 2 + t][r] + b1c[t]));
        }
      __syncthreads();  // hidden visible
      if (cc < 3) load_b8(P + (5 + cc) * PANEL, Ba, nl, q8, w2t);  // next w1
      mfma32v(sm.kvb, Bb, xd, nl, q8, cc == 0);
      if (cc < 3) __syncthreads();  // hidden reads done before next overwrite
    }
#pragma unroll
    for (int rt = 0; rt < 2; ++rt)
#pragma unroll
      for (int t = 0; t < 2; ++t)
#pragma unroll
        for (int r = 0; r < 4; ++r)
          xr[rt][t][r] += xd[rt * 2 + t][r] + b2r[t];
  }  // layers

  // ---- final: xq = LN(x)@wqf+bqf ; ctxp = LN(ctx)@wcf+bcf ; softmax over 9 ----
  float bqfr[2], bcfr[2];
#pragma unroll
  for (int t = 0; t < 2; ++t) {
    const int n = (w2t + t) * 16 + nl;
    bqfr[t] = bqf[n];
    bcfr[t] = bcf[n];
  }
  load_b8(wsp + 24 * PANEL, Ba, nl, q8, w2t);
  load_b8(wsp + 25 * PANEL, Bb, nl, q8, w2t);
  ln_x(xr, sm.xn, sm.scratch, wave, nl, qm);
  mfma32v(sm.xn, Ba, acc4, nl, q8, true);   // xq (kept in acc4)
  gemm72_store(sm.ctxn, Bb, sm.kvb, bcfr, nl, q8, qm, w2t);  // ctxp
  __syncthreads();  // ctxp visible; xn reads done
#pragma unroll
  for (int rt = 0; rt < 2; ++rt)
#pragma unroll
    for (int t = 0; t < 2; ++t) {
      const int n = (w2t + t) * 16 + nl;
#pragma unroll
      for (int r = 0; r < 4; ++r)
        sm.xn[(rt * 16 + qm + r) * CBS + n] = f2bf(acc4[rt * 2 + t][r] + bqfr[t]);
    }
  __syncthreads();  // xq visible
  {
    const int px = tid >> 3, sub = tid & 7;
    const int lr = (((px >> 3) >> 1) << 2) | ((px & 7) >> 1);
    const unsigned short* qrow = sm.xn + px * CBS;
#pragma unroll
    for (int which = 0; which < 2; ++which) {
      if (which == 1 && sub != 0) break;
      const int kk = (which == 0) ? sub : 8;
      const unsigned short* crow = sm.kvb + (lr * 9 + kk) * CBS;
      float s = 0.f;
#pragma unroll
      for (int c8 = 0; c8 < 16; ++c8) {
        const u16x8 qa = *reinterpret_cast<const u16x8*>(qrow + c8 * 8);
        const u16x8 ca = *reinterpret_cast<const u16x8*>(crow + c8 * 8);
#pragma unroll
        for (int j = 0; j < 8; ++j) s += bf2f(qa[j]) * bf2f(ca[j]);
      }
      sm.scratch[MSC_ATT + px * 12 + kk] = s;
    }
  }
  __syncthreads();
  if (tid < 32) {
    const int px = tid;
    const int hu = hu0 + (px >> 3), wu = wu0 + (px & 7);
    float lg[9], mx = -1e30f;
#pragma unroll
    for (int kk = 0; kk < 9; ++kk) {
      lg[kk] = sm.scratch[MSC_ATT + px * 12 + kk] * 0.08838834764831845f;
      mx = fmaxf(mx, lg[kk]);
    }
    float sum = 0.f;
#pragma unroll
    for (int kk = 0; kk < 9; ++kk) { lg[kk] = __expf(lg[kk] - mx); sum += lg[kk]; }
    const float inv = 1.f / sum;
#pragma unroll
    for (int kk = 0; kk < 9; ++kk)
      out[((bz * 9 + kk) * HuC + hu) * WuC + wu] = lg[kk] * inv;
  }
}

}  // namespace

extern "C" void kernel_launch(void* const* d_in, const int* in_sizes, int n_in,
                              void* d_out, int out_size, void* d_ws, size_t ws_size,
                              hipStream_t stream) {
  const float* fm   = (const float*)d_in[0];
  const float* fmu  = (const float*)d_in[1];
  const float* nc_w = (const float*)d_in[2];
  const float* nc_b = (const float*)d_in[3];
  const float* wq   = (const float*)d_in[4];
  const float* bq   = (const float*)d_in[5];
  const float* wkv  = (const float*)d_in[6];
  const float* bkv  = (const float*)d_in[7];
  const float* wo   = (const float*)d_in[8];
  const float* bo   = (const float*)d_in[9];
  const float* w1   = (const float*)d_in[10];
  const float* b1   = (const float*)d_in[11];
  const float* w2   = (const float*)d_in[12];
  const float* b2   = (const float*)d_in[13];
  const float* wqf  = (const float*)d_in[14];
  const float* bqf  = (const float*)d_in[15];
  const float* wcf  = (const float*)d_in[16];
  const float* bcf  = (const float*)d_in[17];
  float* out = (float*)d_out;

  dim3 grid(24, 32, 2);  // 4x8-pixel tiles
  if (ws_size >= WS_NEEDED) {
    unsigned short* wsp = (unsigned short*)d_ws;
    float* wsb = (float*)((char*)d_ws + (size_t)N_PANELS * PANEL * 2);
    prep_weights<<<dim3(106), dim3(256), 0, stream>>>(
        nc_w, nc_b, wq, wkv, bkv, wo, w1, w2, wqf, wcf, wsp, wsb);
    fused_interp_mfma<<<grid, dim3(THREADS), 0, stream>>>(
        fm, fmu, bq, bo, b1, b2, bqf, bcf, wsp, wsb, out);
  } else {
    fused_interp_kernel<<<grid, dim3(THREADS), 0, stream>>>(
        fm, fmu, nc_w, nc_b, wq, bq, wkv, bkv, wo, bo, w1, b1, w2, b2,
        wqf, bqf, wcf, bcf, out);
  }
}

// Round 11
// 301.791 us; speedup vs baseline: 1.3044x; 1.2965x over previous
//
#include <hip/hip_runtime.h>

namespace {

constexpr int THREADS = 256;
constexpr int HdC = 64, WdC = 96, HuC = 128, WuC = 192;

// ======================= shared helpers =======================

__device__ __forceinline__ float gelu_tanh(float x) {
  float z = 0.7978845608028654f * (x + 0.044715f * x * x * x);
  float e = __expf(2.0f * z);
  float t = 1.0f - 2.0f / (e + 1.0f);
  return 0.5f * x * (1.0f + t);
}

__device__ __forceinline__ unsigned short f2bf(float f) {
  unsigned int u = __builtin_bit_cast(unsigned int, f);
  u = (u + 0x7FFFu + ((u >> 16) & 1u)) >> 16;  // RNE
  return (unsigned short)u;
}

__device__ __forceinline__ float bf2f(unsigned short u) {
  unsigned int x = ((unsigned int)u) << 16;
  return __builtin_bit_cast(float, x);
}

// ======================= fp32 fallback path (round-1, verified) =======================

constexpr int CTX_S = 80;
constexpr int KV_S  = 132;
constexpr int XS_S  = 132;
constexpr int XN_S  = 32;
constexpr int OB_S  = 144;

constexpr int SC_ATT = 0;
constexpr int SC_RED = 0;
constexpr int SC_MU  = 768;
constexpr int SC_RS  = 864;
constexpr int SC_NC  = 1152;
constexpr int SC_LG  = 0;

struct alignas(16) Smem {
  float ctxT[128 * CTX_S];
  float kvb[72 * KV_S];
  float xs[32 * XS_S];
  float xnT[128 * XN_S];
  float outb[32 * OB_S];
  float wbuf[32 * 128];
  float scratch[1536];
};
static_assert(sizeof(Smem) <= 160 * 1024, "LDS budget");

__device__ __forceinline__ void stage_w(const float* __restrict__ W, int wstride,
                                        int kc, float* wbuf, int tid) {
#pragma unroll
  for (int p = 0; p < 4; ++p) {
    int e = tid + p * THREADS;
    int r = e >> 5;
    int c4 = (e & 31) << 2;
    const float4 v = *reinterpret_cast<const float4*>(W + (kc * 32 + r) * wstride + c4);
    *reinterpret_cast<float4*>(wbuf + r * 128 + c4) = v;
  }
}

#define FMA_ROW(ac, s, w)                                            \
  {                                                                  \
    (ac)[0] += (s) * (w).x; (ac)[1] += (s) * (w).y;                  \
    (ac)[2] += (s) * (w).z; (ac)[3] += (s) * (w).w;                  \
  }

__device__ __forceinline__ void gemm32(const float* __restrict__ W, int wstride,
                                       const float* AT, float* wbuf, int tid,
                                       float acc[16]) {
  const int row0 = (tid >> 5) << 2;
  const int col0 = (tid & 31) << 2;
#pragma unroll
  for (int i = 0; i < 16; ++i) acc[i] = 0.f;
  for (int kc = 0; kc < 4; ++kc) {
    __syncthreads();
    stage_w(W, wstride, kc, wbuf, tid);
    __syncthreads();
#pragma unroll 4
    for (int cl = 0; cl < 32; ++cl) {
      const int c = (kc << 5) + cl;
      const float4 a = *reinterpret_cast<const float4*>(AT + c * XN_S + row0);
      const float4 w = *reinterpret_cast<const float4*>(wbuf + cl * 128 + col0);
      FMA_ROW(acc + 0, a.x, w);
      FMA_ROW(acc + 4, a.y, w);
      FMA_ROW(acc + 8, a.z, w);
      FMA_ROW(acc + 12, a.w, w);
    }
  }
}

template <bool NC>
__device__ __forceinline__ void gemm96(const float* __restrict__ W, int wstride,
                                       const float* ctxT, float* wbuf, float* kvb,
                                       const float* __restrict__ bias,
                                       const float* nc, int tid) {
  const int rt4 = (tid >> 5) << 2;
  const int col0 = (tid & 31) << 2;
  float acc[48];
#pragma unroll
  for (int i = 0; i < 48; ++i) acc[i] = 0.f;
  for (int kc = 0; kc < 4; ++kc) {
    __syncthreads();
    stage_w(W, wstride, kc, wbuf, tid);
    __syncthreads();
#pragma unroll 2
    for (int cl = 0; cl < 32; ++cl) {
      const int c = (kc << 5) + cl;
      const float4 w = *reinterpret_cast<const float4*>(wbuf + cl * 128 + col0);
      float s = 0.f, t = 0.f;
      if (NC) { s = nc[c]; t = nc[128 + c]; }
      const float* base = ctxT + c * CTX_S;
#pragma unroll
      for (int p = 0; p < 3; ++p) {
        int r0 = p * 32 + rt4;
        if (r0 > 76) r0 = 76;
        float4 a = *reinterpret_cast<const float4*>(base + r0);
        if (NC) {
          a.x = a.x * s + t; a.y = a.y * s + t;
          a.z = a.z * s + t; a.w = a.w * s + t;
        }
        float* ac = acc + p * 16;
        FMA_ROW(ac + 0, a.x, w);
        FMA_ROW(ac + 4, a.y, w);
        FMA_ROW(ac + 8, a.z, w);
        FMA_ROW(ac + 12, a.w, w);
      }
    }
  }
  const float4 bv = *reinterpret_cast<const float4*>(bias + col0);
#pragma unroll
  for (int p = 0; p < 3; ++p) {
    const int r0 = p * 32 + rt4;
    if (r0 < 72) {
#pragma unroll
      for (int i = 0; i < 4; ++i) {
        float4 o;
        o.x = acc[p * 16 + i * 4 + 0] + bv.x;
        o.y = acc[p * 16 + i * 4 + 1] + bv.y;
        o.z = acc[p * 16 + i * 4 + 2] + bv.z;
        o.w = acc[p * 16 + i * 4 + 3] + bv.w;
        *reinterpret_cast<float4*>(kvb + (r0 + i) * KV_S + col0) = o;
      }
    }
  }
}

__device__ __forceinline__ void layernorm_x(const float* xs, float* xnT,
                                            float* scratch, int tid) {
  const int px = tid & 31;
  const int cg = tid >> 5;
  float s1 = 0.f, s2 = 0.f;
#pragma unroll
  for (int i = 0; i < 16; ++i) {
    const float v = xs[px * XS_S + cg * 16 + i];
    s1 += v; s2 += v * v;
  }
  scratch[SC_RED + cg * 96 + px] = s1;
  scratch[SC_RED + cg * 96 + 48 + px] = s2;
  __syncthreads();
  if (tid < 32) {
    float a = 0.f, b = 0.f;
#pragma unroll
    for (int g = 0; g < 8; ++g) {
      a += scratch[SC_RED + g * 96 + tid];
      b += scratch[SC_RED + g * 96 + 48 + tid];
    }
    const float m = a * (1.f / 128.f);
    const float v = b * (1.f / 128.f) - m * m;
    scratch[SC_MU + tid] = m;
    scratch[SC_RS + tid] = rsqrtf(v + 1e-6f);
  }
  __syncthreads();
  const float m = scratch[SC_MU + px];
  const float r = scratch[SC_RS + px];
#pragma unroll
  for (int i = 0; i < 16; ++i) {
    const int c = cg * 16 + i;
    xnT[c * XN_S + px] = (xs[px * XS_S + c] - m) * r;
  }
}

__global__ __launch_bounds__(THREADS, 1) void fused_interp_kernel(
    const float* __restrict__ fm, const float* __restrict__ fmu,
    const float* __restrict__ nc_w, const float* __restrict__ nc_b,
    const float* __restrict__ wq, const float* __restrict__ bq,
    const float* __restrict__ wkv, const float* __restrict__ bkv,
    const float* __restrict__ wo, const float* __restrict__ bo,
    const float* __restrict__ w1, const float* __restrict__ b1,
    const float* __restrict__ w2, const float* __restrict__ b2,
    const float* __restrict__ wqf, const float* __restrict__ bqf,
    const float* __restrict__ wcf, const float* __restrict__ bcf,
    float* __restrict__ out) {
  __shared__ Smem sm;
  const int tid = threadIdx.x;
  const int bx = blockIdx.x;
  const int by = blockIdx.y;
  const int bz = blockIdx.z;
  const int lh0 = by * 2, lw0 = bx * 4;
  const int hu0 = by * 4, wu0 = bx * 8;

#pragma unroll
  for (int p = 0; p < 16; ++p) {
    const int idx = tid + p * THREADS;
    const int c = idx >> 5;
    const int px = idx & 31;
    const int hu = hu0 + (px >> 3);
    const int wu = wu0 + (px & 7);
    sm.xs[px * XS_S + c] = fmu[((bz * 128 + c) * HuC + hu) * WuC + wu];
  }

  for (int pass = 0; pass < 2; ++pass) {
    const int rl = tid >> 2;
    const int sub = tid & 3;
    const int r = pass * 64 + rl;
    const bool act = (r < 72);
    int base = 0;
    if (act) {
      const int lr = r / 9, kk = r % 9;
      const int hdp = lh0 + (lr >> 2);
      const int wdp = lw0 + (lr & 3);
      const int ki = kk / 3, kj = kk % 3;
      int hs = hdp + ki - 1; hs = hs < 0 ? 0 : (hs > HdC - 1 ? HdC - 1 : hs);
      int ws = wdp + kj - 1; ws = ws < 0 ? 0 : (ws > WdC - 1 ? WdC - 1 : ws);
      base = (bz * 128) * HdC * WdC + hs * WdC + ws;
      float s1 = 0.f, s2 = 0.f;
      for (int i = 0; i < 32; ++i) {
        const float v = fm[base + (sub * 32 + i) * (HdC * WdC)];
        s1 += v; s2 += v * v;
      }
      sm.scratch[SC_RED + sub * 64 + rl] = s1;
      sm.scratch[SC_RED + 384 + sub * 64 + rl] = s2;
    }
    __syncthreads();
    if (tid < 64 && pass * 64 + tid < 72) {
      float a = 0.f, b = 0.f;
#pragma unroll
      for (int s = 0; s < 4; ++s) {
        a += sm.scratch[SC_RED + s * 64 + tid];
        b += sm.scratch[SC_RED + 384 + s * 64 + tid];
      }
      const float m = a * (1.f / 128.f);
      const float v = b * (1.f / 128.f) - m * m;
      sm.scratch[SC_MU + pass * 64 + tid] = m;
      sm.scratch[SC_RS + pass * 64 + tid] = rsqrtf(v + 1e-6f);
    }
    __syncthreads();
    if (act) {
      const float m = sm.scratch[SC_MU + r];
      const float rr = sm.scratch[SC_RS + r];
      for (int i = 0; i < 32; ++i) {
        const int c = sub * 32 + i;
        const float v = fm[base + c * (HdC * WdC)];
        sm.ctxT[c * CTX_S + r] = (v - m) * rr;
      }
    }
    __syncthreads();
  }
  if (tid < 128) {
#pragma unroll
    for (int r = 72; r < 80; ++r) sm.ctxT[tid * CTX_S + r] = 0.f;
  }
  __syncthreads();

  const int row0 = (tid >> 5) << 2;
  const int col0 = (tid & 31) << 2;
  float acc[16];

  for (int l = 0; l < 2; ++l) {
    if (tid < 128) sm.scratch[SC_NC + tid] = nc_w[l * 128 + tid];
    else           sm.scratch[SC_NC + tid] = nc_b[l * 128 + (tid - 128)];

    layernorm_x(sm.xs, sm.xnT, sm.scratch, tid);
    gemm32(wq + l * 16384, 128, sm.xnT, sm.wbuf, tid, acc);
    {
      const float4 bv = *reinterpret_cast<const float4*>(bq + l * 128 + col0);
#pragma unroll
      for (int i = 0; i < 4; ++i) {
        float4 o;
        o.x = acc[i * 4 + 0] + bv.x; o.y = acc[i * 4 + 1] + bv.y;
        o.z = acc[i * 4 + 2] + bv.z; o.w = acc[i * 4 + 3] + bv.w;
        *reinterpret_cast<float4*>(sm.outb + (row0 + i) * OB_S + col0) = o;
      }
    }
    gemm96<true>(wkv + l * 32768, 256, sm.ctxT, sm.wbuf, sm.kvb,
                 bkv + l * 256, sm.scratch + SC_NC, tid);
    __syncthreads();
    if (tid < 128) {
      const int px = tid >> 2, h = tid & 3;
      const int lr = (((px >> 3) >> 1) << 2) | ((px & 7) >> 1);
      const float* qrow = sm.outb + px * OB_S + h * 32;
      float4 q[8];
#pragma unroll
      for (int d = 0; d < 8; ++d) q[d] = *reinterpret_cast<const float4*>(qrow + d * 4);
      float lg[9];
      float mx = -1e30f;
#pragma unroll
      for (int kk = 0; kk < 9; ++kk) {
        const float* krow = sm.kvb + (lr * 9 + kk) * KV_S + h * 32;
        float s = 0.f;
#pragma unroll
        for (int d = 0; d < 8; ++d) {
          const float4 kv = *reinterpret_cast<const float4*>(krow + d * 4);
          s += q[d].x * kv.x + q[d].y * kv.y + q[d].z * kv.z + q[d].w * kv.w;
        }
        s *= 0.17677669529663687f;
        lg[kk] = s;
        mx = fmaxf(mx, s);
      }
      float sum = 0.f;
#pragma unroll
      for (int kk = 0; kk < 9; ++kk) { lg[kk] = __expf(lg[kk] - mx); sum += lg[kk]; }
      const float inv = 1.f / sum;
#pragma unroll
      for (int kk = 0; kk < 9; ++kk)
        sm.scratch[SC_ATT + (px * 4 + h) * 9 + kk] = lg[kk] * inv;
    }
    __syncthreads();
    gemm96<true>(wkv + l * 32768 + 128, 256, sm.ctxT, sm.wbuf, sm.kvb,
                 bkv + l * 256 + 128, sm.scratch + SC_NC, tid);
    __syncthreads();
    {
      const int c = tid & 127, pg = tid >> 7;
      const int h = c >> 5;
#pragma unroll 4
      for (int i = 0; i < 16; ++i) {
        const int px = pg * 16 + i;
        const int lr = (((px >> 3) >> 1) << 2) | ((px & 7) >> 1);
        const float* aw = sm.scratch + SC_ATT + (px * 4 + h) * 9;
        float s = 0.f;
#pragma unroll
        for (int kk = 0; kk < 9; ++kk) s += aw[kk] * sm.kvb[(lr * 9 + kk) * KV_S + c];
        sm.xnT[c * XN_S + px] = s;
      }
    }
    gemm32(wo + l * 16384, 128, sm.xnT, sm.wbuf, tid, acc);
    {
      const float4 bv = *reinterpret_cast<const float4*>(bo + l * 128 + col0);
#pragma unroll
      for (int i = 0; i < 4; ++i) {
        float* xr = sm.xs + (row0 + i) * XS_S + col0;
        float4 x = *reinterpret_cast<float4*>(xr);
        x.x += acc[i * 4 + 0] + bv.x; x.y += acc[i * 4 + 1] + bv.y;
        x.z += acc[i * 4 + 2] + bv.z; x.w += acc[i * 4 + 3] + bv.w;
        *reinterpret_cast<float4*>(xr) = x;
      }
    }
    __syncthreads();
    layernorm_x(sm.xs, sm.xnT, sm.scratch, tid);
    float xd[16];
#pragma unroll
    for (int i = 0; i < 16; ++i) xd[i] = 0.f;
    for (int cc = 0; cc < 4; ++cc) {
      gemm32(w1 + l * 65536 + cc * 128, 512, sm.xnT, sm.wbuf, tid, acc);
      {
        const float4 bv = *reinterpret_cast<const float4*>(b1 + l * 512 + cc * 128 + col0);
#pragma unroll
        for (int i = 0; i < 4; ++i) {
          float4 o;
          o.x = gelu_tanh(acc[i * 4 + 0] + bv.x);
          o.y = gelu_tanh(acc[i * 4 + 1] + bv.y);
          o.z = gelu_tanh(acc[i * 4 + 2] + bv.z);
          o.w = gelu_tanh(acc[i * 4 + 3] + bv.w);
          *reinterpret_cast<float4*>(sm.outb + (row0 + i) * OB_S + col0) = o;
        }
      }
      __syncthreads();
      const float* w2c = w2 + l * 65536 + cc * 16384;
      for (int kc = 0; kc < 4; ++kc) {
        __syncthreads();
        stage_w(w2c, 128, kc, sm.wbuf, tid);
        __syncthreads();
#pragma unroll 4
        for (int cl = 0; cl < 32; ++cl) {
          const int c = (kc << 5) + cl;
          const float a0 = sm.outb[(row0 + 0) * OB_S + c];
          const float a1 = sm.outb[(row0 + 1) * OB_S + c];
          const float a2 = sm.outb[(row0 + 2) * OB_S + c];
          const float a3 = sm.outb[(row0 + 3) * OB_S + c];
          const float4 w = *reinterpret_cast<const float4*>(sm.wbuf + cl * 128 + col0);
          FMA_ROW(xd + 0, a0, w);
          FMA_ROW(xd + 4, a1, w);
          FMA_ROW(xd + 8, a2, w);
          FMA_ROW(xd + 12, a3, w);
        }
      }
    }
    {
      const float4 bv = *reinterpret_cast<const float4*>(b2 + l * 128 + col0);
#pragma unroll
      for (int i = 0; i < 4; ++i) {
        float* xr = sm.xs + (row0 + i) * XS_S + col0;
        float4 x = *reinterpret_cast<float4*>(xr);
        x.x += xd[i * 4 + 0] + bv.x; x.y += xd[i * 4 + 1] + bv.y;
        x.z += xd[i * 4 + 2] + bv.z; x.w += xd[i * 4 + 3] + bv.w;
        *reinterpret_cast<float4*>(xr) = x;
      }
    }
    __syncthreads();
  }

  layernorm_x(sm.xs, sm.xnT, sm.scratch, tid);
  gemm32(wqf, 128, sm.xnT, sm.wbuf, tid, acc);
  {
    const float4 bv = *reinterpret_cast<const float4*>(bqf + col0);
#pragma unroll
    for (int i = 0; i < 4; ++i) {
      float4 o;
      o.x = acc[i * 4 + 0] + bv.x; o.y = acc[i * 4 + 1] + bv.y;
      o.z = acc[i * 4 + 2] + bv.z; o.w = acc[i * 4 + 3] + bv.w;
      *reinterpret_cast<float4*>(sm.outb + (row0 + i) * OB_S + col0) = o;
    }
  }
  gemm96<false>(wcf, 128, sm.ctxT, sm.wbuf, sm.kvb, bcf, nullptr, tid);
  __syncthreads();
  {
    const int px = tid >> 3, sub = tid & 7;
    const int lr = (((px >> 3) >> 1) << 2) | ((px & 7) >> 1);
    const float* qrow = sm.outb + px * OB_S;
    {
      const float* crow = sm.kvb + (lr * 9 + sub) * KV_S;
      float s = 0.f;
#pragma unroll 8
      for (int c = 0; c < 128; c += 4) {
        const float4 qv = *reinterpret_cast<const float4*>(qrow + c);
        const float4 cv = *reinterpret_cast<const float4*>(crow + c);
        s += qv.x * cv.x + qv.y * cv.y + qv.z * cv.z + qv.w * cv.w;
      }
      sm.scratch[SC_LG + px * 12 + sub] = s;
    }
    if (sub == 0) {
      const float* crow = sm.kvb + (lr * 9 + 8) * KV_S;
      float s = 0.f;
#pragma unroll 8
      for (int c = 0; c < 128; c += 4) {
        const float4 qv = *reinterpret_cast<const float4*>(qrow + c);
        const float4 cv = *reinterpret_cast<const float4*>(crow + c);
        s += qv.x * cv.x + qv.y * cv.y + qv.z * cv.z + qv.w * cv.w;
      }
      sm.scratch[SC_LG + px * 12 + 8] = s;
    }
  }
  __syncthreads();
  if (tid < 32) {
    const int px = tid;
    const int hu = hu0 + (px >> 3), wu = wu0 + (px & 7);
    float lg[9], mx = -1e30f;
#pragma unroll
    for (int kk = 0; kk < 9; ++kk) {
      lg[kk] = sm.scratch[SC_LG + px * 12 + kk] * 0.08838834764831845f;
      mx = fmaxf(mx, lg[kk]);
    }
    float sum = 0.f;
#pragma unroll
    for (int kk = 0; kk < 9; ++kk) { lg[kk] = __expf(lg[kk] - mx); sum += lg[kk]; }
    const float inv = 1.f / sum;
#pragma unroll
    for (int kk = 0; kk < 9; ++kk)
      out[((bz * 9 + kk) * HuC + hu) * WuC + wu] = lg[kk] * inv;
  }
}

// ======================= MFMA path (v11) =======================
// r7 envelope (2 blocks/CU, 2 waves/SIMD, no spills) + dedup: the 72 context
// rows contain only 24 distinct patch pixels, so k/v/ctxp are computed as
// 32-row GEMMs (24 used) and attention indexes by patch pixel pp. Cuts the
// dominant GEMMs 2.25x and context-LN 3x. LDS ~40 KB.

constexpr int PANEL = 16384;              // u16 per 128x128 panel, [n][k] layout
constexpr int N_PANELS = 26;
constexpr size_t WS_NEEDED = (size_t)N_PANELS * PANEL * 2 + 2048;
constexpr int CBS = 136;                  // bf16 LDS row stride
constexpr int XTS = 132;                  // fp32 temp stride

constexpr int MSC_ATT = 0;                // 1152: attn probs; aliased by LN/patch partials/logits
constexpr int MSC_LN  = 0;                // 256: LN partials (alias)
constexpr int MSC_ST  = 1152;             // 48: patch stats
constexpr int MSC_N   = 1200;

typedef __attribute__((ext_vector_type(8))) short bf16x8;
typedef __attribute__((ext_vector_type(4))) float f32x4;
typedef __attribute__((ext_vector_type(8))) unsigned short u16x8;

struct alignas(16) SmemM {
  unsigned short ctxn[32 * CBS];    // 8704 B: LN(patch) bf16, rows 0..23 valid
  unsigned short kvb[32 * CBS];     // 8704 B: k/v/ctxp by patch pixel; MLP hidden
  unsigned short xn[32 * CBS];      // 8704 B: LN(x) / o
  unsigned short outb[32 * CBS];    // 8704 B: q / xq
  float scratch[MSC_N];             // 4800 B
};
// kvb+xn+outb are contiguous (26112 B): aliased as fp32 xtmp[32*132]=16896 B
// and fp32 patch[24*132]=12672 B during phase 0 (ctxn stays disjoint).
static_assert(sizeof(SmemM) <= 44 * 1024, "LDS budget");

__global__ void prep_weights(
    const float* __restrict__ nc_w, const float* __restrict__ nc_b,
    const float* __restrict__ wq, const float* __restrict__ wkv,
    const float* __restrict__ bkv,
    const float* __restrict__ wo, const float* __restrict__ w1,
    const float* __restrict__ w2, const float* __restrict__ wqf,
    const float* __restrict__ wcf,
    unsigned short* __restrict__ wsp, float* __restrict__ wsb) {
  const int b = blockIdx.x;
  const int t = threadIdx.x;
  if (b >= 104) {  // adjusted kv bias: b' = bkv + nc_b @ wkv
    const int l = b - 104;
    float acc = bkv[l * 256 + t];
    for (int k = 0; k < 128; ++k)
      acc += nc_b[l * 128 + k] * wkv[l * 32768 + k * 256 + t];
    wsb[l * 256 + t] = acc;
    return;
  }
  const int pid = b >> 2, qtr = b & 3;
  const float* src = wqf; int N = 128, koff = 0, noff = 0;
  const float* sc = nullptr;
  if (pid < 24) {
    const int l = pid / 12, loc = pid % 12;
    if (loc == 0)      { src = wq + l * 16384;  N = 128; }
    else if (loc == 1) { src = wkv + l * 32768; N = 256; sc = nc_w + l * 128; }
    else if (loc == 2) { src = wkv + l * 32768; N = 256; noff = 128; sc = nc_w + l * 128; }
    else if (loc == 3) { src = wo + l * 16384;  N = 128; }
    else if (loc < 8)  { src = w1 + l * 65536;  N = 512; noff = (loc - 4) * 128; }
    else               { src = w2 + l * 65536;  N = 128; koff = (loc - 8) * 128; }
  } else if (pid == 25) { src = wcf; }
  unsigned short* dst = wsp + pid * PANEL;
#pragma unroll
  for (int p = 0; p < 2; ++p) {
    const int e = t + p * 256;
    const int n = e & 127;
    const int kg = e >> 7;
    const int k0 = qtr * 32 + kg * 8;
    unsigned short tmp[8];
#pragma unroll
    for (int i = 0; i < 8; ++i) {
      const float s = sc ? sc[k0 + i] : 1.f;
      tmp[i] = f2bf(src[(k0 + i + koff) * N + noff + n] * s);
    }
    *reinterpret_cast<u16x8*>(dst + n * 128 + k0) = *reinterpret_cast<u16x8*>(tmp);
  }
}

// load 2 col-tiles x 4 k-slices of B fragments (tiles 2*wave, 2*wave+1)
__device__ __forceinline__ void load_b8(const unsigned short* __restrict__ W,
                                        bf16x8 b[2][4], int nl, int q8, int w2t) {
#pragma unroll
  for (int t = 0; t < 2; ++t)
#pragma unroll
    for (int ks = 0; ks < 4; ++ks)
      b[t][ks] = *reinterpret_cast<const bf16x8*>(
          W + ((w2t + t) * 16 + nl) * 128 + ks * 32 + q8);
}

// 32x128 @ 128x(2 tiles): acc[rt*2+t], both row tiles
__device__ __forceinline__ void mfma32v(const unsigned short* A, const bf16x8 b[2][4],
                                        f32x4 acc[4], int nl, int q8, bool init) {
  if (init) {
#pragma unroll
    for (int i = 0; i < 4; ++i) acc[i] = (f32x4){0.f, 0.f, 0.f, 0.f};
  }
#pragma unroll
  for (int ks = 0; ks < 4; ++ks) {
    const bf16x8 a0 = *reinterpret_cast<const bf16x8*>(A + nl * CBS + ks * 32 + q8);
    const bf16x8 a1 = *reinterpret_cast<const bf16x8*>(A + (16 + nl) * CBS + ks * 32 + q8);
    acc[0] = __builtin_amdgcn_mfma_f32_16x16x32_bf16(a0, b[0][ks], acc[0], 0, 0, 0);
    acc[1] = __builtin_amdgcn_mfma_f32_16x16x32_bf16(a0, b[1][ks], acc[1], 0, 0, 0);
    acc[2] = __builtin_amdgcn_mfma_f32_16x16x32_bf16(a1, b[0][ks], acc[2], 0, 0, 0);
    acc[3] = __builtin_amdgcn_mfma_f32_16x16x32_bf16(a1, b[1][ks], acc[3], 0, 0, 0);
  }
}

// store 32-row gemm result (+bias per col tile) into dst (all 32 rows)
__device__ __forceinline__ void store32(unsigned short* dst, const f32x4 acc[4],
                                        const float bias[2], int nl, int qm, int w2t) {
#pragma unroll
  for (int rt = 0; rt < 2; ++rt)
#pragma unroll
    for (int t = 0; t < 2; ++t) {
      const int n = (w2t + t) * 16 + nl;
#pragma unroll
      for (int r = 0; r < 4; ++r)
        dst[(rt * 16 + qm + r) * CBS + n] = f2bf(acc[rt * 2 + t][r] + bias[t]);
    }
}

// LN of register-resident x (xr[rt][t][r]) -> xn bf16. 2 barriers.
__device__ __forceinline__ void ln_x(const float (&xr)[2][2][4], unsigned short* xn,
                                     float* scratch, int wave, int nl, int qm) {
#pragma unroll
  for (int rt = 0; rt < 2; ++rt)
#pragma unroll
    for (int r = 0; r < 4; ++r) {
      float s1 = xr[rt][0][r] + xr[rt][1][r];
      float s2 = xr[rt][0][r] * xr[rt][0][r] + xr[rt][1][r] * xr[rt][1][r];
#pragma unroll
      for (int m = 1; m < 16; m <<= 1) {
        s1 += __shfl_xor(s1, m, 64);
        s2 += __shfl_xor(s2, m, 64);
      }
      if (nl == 0) {
        const int px = rt * 16 + qm + r;
        scratch[MSC_LN + px * 4 + wave] = s1;
        scratch[MSC_LN + 128 + px * 4 + wave] = s2;
      }
    }
  __syncthreads();
#pragma unroll
  for (int rt = 0; rt < 2; ++rt)
#pragma unroll
    for (int r = 0; r < 4; ++r) {
      const int px = rt * 16 + qm + r;
      float a = 0.f, b = 0.f;
#pragma unroll
      for (int w = 0; w < 4; ++w) {
        a += scratch[MSC_LN + px * 4 + w];
        b += scratch[MSC_LN + 128 + px * 4 + w];
      }
      const float m = a * (1.f / 128.f);
      const float v = b * (1.f / 128.f) - m * m;
      const float rs = rsqrtf(v + 1e-6f);
#pragma unroll
      for (int t = 0; t < 2; ++t)
        xn[px * CBS + (wave * 2 + t) * 16 + nl] = f2bf((xr[rt][t][r] - m) * rs);
    }
  __syncthreads();
}

// patch pixel index for (lr, kk): lr in 2x4 tile, kk = ki*3+kj in 3x3 window
__device__ __forceinline__ int pp_of(int lr, int kk) {
  const int ki = kk / 3, kj = kk - ki * 3;
  return ((lr >> 2) + ki) * 6 + (lr & 3) + kj;
}

__global__ __launch_bounds__(THREADS, 2) void fused_interp_mfma(
    const float* __restrict__ fm, const float* __restrict__ fmu,
    const float* __restrict__ bq, const float* __restrict__ bo,
    const float* __restrict__ b1, const float* __restrict__ b2,
    const float* __restrict__ bqf, const float* __restrict__ bcf,
    const unsigned short* __restrict__ wsp, const float* __restrict__ wsb,
    float* __restrict__ out) {
  __shared__ SmemM sm;
  const int tid = threadIdx.x;
  const int bx = blockIdx.x, by = blockIdx.y, bz = blockIdx.z;
  const int lh0 = by * 2, lw0 = bx * 4;
  const int hu0 = by * 4, wu0 = bx * 8;

  const int lane = tid & 63;
  const int wave = tid >> 6;            // 0..3
  const int nl = lane & 15;
  const int q8 = (lane >> 4) * 8;
  const int qm = (lane >> 4) * 4;
  const int w2t = wave * 2;             // this wave's 2 col tiles

  // ---- phase 0a: x tile -> xtmp in kvb..outb (float2 coalesced), then registers ----
  {
    float* xtmp = reinterpret_cast<float*>(sm.kvb);
#pragma unroll
    for (int p = 0; p < 8; ++p) {
      const int e = tid + p * THREADS;   // 0..2047
      const int pe = e & 15;
      const int c = e >> 4;
      const int hu = hu0 + (pe >> 2);
      const int wu = wu0 + (pe & 3) * 2;
      const float2 v = *reinterpret_cast<const float2*>(
          &fmu[((bz * 128 + c) * HuC + hu) * WuC + wu]);
      const int px = (pe >> 2) * 8 + (pe & 3) * 2;
      xtmp[px * XTS + c] = v.x;
      xtmp[(px + 1) * XTS + c] = v.y;
    }
  }
  __syncthreads();
  float xr[2][2][4];
  {
    const float* xtmp = reinterpret_cast<const float*>(sm.kvb);
#pragma unroll
    for (int rt = 0; rt < 2; ++rt)
#pragma unroll
      for (int t = 0; t < 2; ++t)
#pragma unroll
        for (int r = 0; r < 4; ++r)
          xr[rt][t][r] = xtmp[(rt * 16 + qm + r) * XTS + (w2t + t) * 16 + nl];
  }
  __syncthreads();

  // ---- phase 0b: patch (4 x 6 low-res px, edge-clamped) + LN -> ctxn rows 0..23 ----
  {
    float* patch = reinterpret_cast<float*>(sm.kvb);  // 24*132 fp32, disjoint from ctxn
#pragma unroll
    for (int p = 0; p < 12; ++p) {
      const int e = tid + p * THREADS;  // 0..3071
      const int c = e / 24;
      const int rem = e - c * 24;
      const int hs_i = rem / 6;
      const int ws_i = rem - hs_i * 6;
      int hd = lh0 - 1 + hs_i; hd = hd < 0 ? 0 : (hd > HdC - 1 ? HdC - 1 : hd);
      int wd = lw0 - 1 + ws_i; wd = wd < 0 ? 0 : (wd > WdC - 1 ? WdC - 1 : wd);
      patch[(hs_i * 6 + ws_i) * XTS + c] = fm[((bz * 128 + c) * HdC + hd) * WdC + wd];
    }
  }
  __syncthreads();
  {
    const float* patch = reinterpret_cast<const float*>(sm.kvb);
    if (tid < 192) {
      const int pp = tid >> 3, part = tid & 7;
      float s1 = 0.f, s2 = 0.f;
#pragma unroll
      for (int i = 0; i < 16; ++i) {
        const float v = patch[pp * XTS + part * 16 + i];
        s1 += v; s2 += v * v;
      }
      sm.scratch[MSC_ATT + tid * 2 + 0] = s1;
      sm.scratch[MSC_ATT + tid * 2 + 1] = s2;
    }
    __syncthreads();
    if (tid < 24) {
      float a = 0.f, b = 0.f;
#pragma unroll
      for (int g = 0; g < 8; ++g) {
        a += sm.scratch[MSC_ATT + (tid * 8 + g) * 2 + 0];
        b += sm.scratch[MSC_ATT + (tid * 8 + g) * 2 + 1];
      }
      const float m = a * (1.f / 128.f);
      const float v = b * (1.f / 128.f) - m * m;
      sm.scratch[MSC_ST + tid * 2 + 0] = m;
      sm.scratch[MSC_ST + tid * 2 + 1] = rsqrtf(v + 1e-6f);
    }
    __syncthreads();
    // 24 rows x 16 chunks = 384 vector writes
    {
      const int e = tid;
      if (e < 192) {
        const int r = e >> 3, cg = e & 7;   // split: threads 0..191 do rows 0..23, 8 chunks
        const float m = sm.scratch[MSC_ST + r * 2 + 0];
        const float rs = sm.scratch[MSC_ST + r * 2 + 1];
        unsigned short tmp[16];
#pragma unroll
        for (int j = 0; j < 16; ++j)
          tmp[j] = f2bf((patch[r * XTS + cg * 16 + j] - m) * rs);
        *reinterpret_cast<u16x8*>(sm.ctxn + r * CBS + cg * 16) = *reinterpret_cast<u16x8*>(tmp);
        *reinterpret_cast<u16x8*>(sm.ctxn + r * CBS + cg * 16 + 8) = *reinterpret_cast<u16x8*>(tmp + 8);
      }
    }
  }
  __syncthreads();  // ctxn rows 0..23 ready; patch dead -> kvb/xn/outb free

  f32x4 acc4[4];
  f32x4 acck[4];
  bf16x8 Ba[2][4], Bb[2][4];   // short-lived; never live across a loop back-edge

  for (int l = 0; l < 2; ++l) {
    const unsigned short* P = wsp + (l * 12) * PANEL;

    // preload biases for this layer
    float kb[2], vb[2], bqr[2], bor[2], b2r[2];
#pragma unroll
    for (int t = 0; t < 2; ++t) {
      const int n = (w2t + t) * 16 + nl;
      kb[t] = wsb[l * 256 + n];
      vb[t] = wsb[l * 256 + 128 + n];
      bqr[t] = bq[l * 128 + n];
      bor[t] = bo[l * 128 + n];
      b2r[t] = b2[l * 128 + n];
    }

    // q/k panels in flight during ln_x
    load_b8(P + 0 * PANEL, Ba, nl, q8, w2t);
    load_b8(P + 1 * PANEL, Bb, nl, q8, w2t);
    ln_x(xr, sm.xn, sm.scratch, wave, nl, qm);

    // q = LN(x) @ wq + bq -> outb ; k = ctxn(24r) @ wkv_k + b' -> kvb
    mfma32v(sm.xn, Ba, acc4, nl, q8, true);
    mfma32v(sm.ctxn, Bb, acck, nl, q8, true);
    load_b8(P + 2 * PANEL, Ba, nl, q8, w2t);  // v panel, in flight through softmax
    store32(sm.outb, acc4, bqr, nl, qm, w2t);
    store32(sm.kvb, acck, kb, nl, qm, w2t);
    __syncthreads();  // q, k visible

    // attention softmax: 256 threads, 2 per (px,h), kk split 5/4; k indexed by pp
    {
      const int u = tid >> 1, sub = tid & 1;
      const int px = u >> 2, h = u & 3;
      const int lr = (((px >> 3) >> 1) << 2) | ((px & 7) >> 1);
      const unsigned short* qrow = sm.outb + px * CBS + h * 32;
      const int base = sub ? 5 : 0;
      const int cnt = sub ? 4 : 5;
      float mine[5];
#pragma unroll
      for (int i = 0; i < 5; ++i) mine[i] = 0.f;
#pragma unroll
      for (int c8 = 0; c8 < 4; ++c8) {
        const u16x8 qa = *reinterpret_cast<const u16x8*>(qrow + c8 * 8);
        float qaf[8];
#pragma unroll
        for (int j = 0; j < 8; ++j) qaf[j] = bf2f(qa[j]);
#pragma unroll
        for (int i = 0; i < 5; ++i) {
          if (i < cnt) {
            const int pp = pp_of(lr, base + i);
            const u16x8 ka = *reinterpret_cast<const u16x8*>(
                sm.kvb + pp * CBS + h * 32 + c8 * 8);
            float s = 0.f;
#pragma unroll
            for (int j = 0; j < 8; ++j) s += qaf[j] * bf2f(ka[j]);
            mine[i] += s;
          }
        }
      }
#pragma unroll
      for (int i = 0; i < 5; ++i) mine[i] *= 0.17677669529663687f;  // 1/sqrt(32)
      float other[5];
#pragma unroll
      for (int i = 0; i < 5; ++i) other[i] = __shfl_xor(mine[i], 1, 64);
      float lg[9];
#pragma unroll
      for (int j = 0; j < 5; ++j) lg[j] = sub ? other[j] : mine[j];
#pragma unroll
      for (int j = 0; j < 4; ++j) lg[5 + j] = sub ? mine[j] : other[j];
      float mx = -1e30f;
#pragma unroll
      for (int kk = 0; kk < 9; ++kk) mx = fmaxf(mx, lg[kk]);
      float sum = 0.f;
#pragma unroll
      for (int kk = 0; kk < 9; ++kk) { lg[kk] = __expf(lg[kk] - mx); sum += lg[kk]; }
      const float inv = 1.f / sum;
#pragma unroll
      for (int j = 0; j < 5; ++j)
        if (j < cnt) sm.scratch[MSC_ATT + (px * 4 + h) * 9 + base + j] = lg[base + j] * inv;
    }
    __syncthreads();  // probs visible; k reads done

    // v = ctxn(24r) @ wkv_v + b' -> kvb (overwrites k)
    mfma32v(sm.ctxn, Ba, acck, nl, q8, true);
    load_b8(P + 3 * PANEL, Bb, nl, q8, w2t);  // wo panel, in flight through o-section
    store32(sm.kvb, acck, vb, nl, qm, w2t);
    __syncthreads();  // v visible

    // o = attn @ v -> xn (v indexed by pp)
    {
      const int px = tid >> 3, cg = tid & 7, c0 = cg * 16;
      const int lr = (((px >> 3) >> 1) << 2) | ((px & 7) >> 1);
      const float* aw = sm.scratch + MSC_ATT + (px * 4 + (cg >> 1)) * 9;
      float o[16];
#pragma unroll
      for (int j = 0; j < 16; ++j) o[j] = 0.f;
#pragma unroll
      for (int kk = 0; kk < 9; ++kk) {
        const float a = aw[kk];
        const int pp = pp_of(lr, kk);
        const unsigned short* vrow = sm.kvb + pp * CBS + c0;
        const u16x8 v0 = *reinterpret_cast<const u16x8*>(vrow);
        const u16x8 v1 = *reinterpret_cast<const u16x8*>(vrow + 8);
#pragma unroll
        for (int j = 0; j < 8; ++j) {
          o[j] += a * bf2f(v0[j]);
          o[8 + j] += a * bf2f(v1[j]);
        }
      }
      unsigned short tmp[16];
#pragma unroll
      for (int j = 0; j < 16; ++j) tmp[j] = f2bf(o[j]);
      *reinterpret_cast<u16x8*>(sm.xn + px * CBS + c0) = *reinterpret_cast<u16x8*>(tmp);
      *reinterpret_cast<u16x8*>(sm.xn + px * CBS + c0 + 8) = *reinterpret_cast<u16x8*>(tmp + 8);
    }
    __syncthreads();  // xn(o) visible

    // x += o @ wo + bo
    mfma32v(sm.xn, Bb, acc4, nl, q8, true);
#pragma unroll
    for (int rt = 0; rt < 2; ++rt)
#pragma unroll
      for (int t = 0; t < 2; ++t)
#pragma unroll
        for (int r = 0; r < 4; ++r)
          xr[rt][t][r] += acc4[rt * 2 + t][r] + bor[t];

    // MLP: w1_cc -> Ba, w2_cc -> Bb; gelu hidden lives in kvb (v dead)
    load_b8(P + 4 * PANEL, Ba, nl, q8, w2t);  // w1_0, in flight through ln_x
    ln_x(xr, sm.xn, sm.scratch, wave, nl, qm);  // 1st internal barrier drains wo reads
    f32x4 xd[4];
    for (int cc = 0; cc < 4; ++cc) {
      float b1c[2];
#pragma unroll
      for (int t = 0; t < 2; ++t)
        b1c[t] = b1[l * 512 + cc * 128 + (w2t + t) * 16 + nl];
      mfma32v(sm.xn, Ba, acc4, nl, q8, true);
      load_b8(P + (8 + cc) * PANEL, Bb, nl, q8, w2t);  // w2_cc, in flight through gelu
#pragma unroll
      for (int rt = 0; rt < 2; ++rt)
#pragma unroll
        for (int t = 0; t < 2; ++t) {
          const int n = (w2t + t) * 16 + nl;
#pragma unroll
          for (int r = 0; r < 4; ++r)
            sm.kvb[(rt * 16 + qm + r) * CBS + n] =
                f2bf(gelu_tanh(acc4[rt * 2 + t][r] + b1c[t]));
        }
      __syncthreads();  // hidden visible
      if (cc < 3) load_b8(P + (5 + cc) * PANEL, Ba, nl, q8, w2t);  // next w1
      mfma32v(sm.kvb, Bb, xd, nl, q8, cc == 0);
      if (cc < 3) __syncthreads();  // hidden reads done before next overwrite
    }
#pragma unroll
    for (int rt = 0; rt < 2; ++rt)
#pragma unroll
      for (int t = 0; t < 2; ++t)
#pragma unroll
        for (int r = 0; r < 4; ++r)
          xr[rt][t][r] += xd[rt * 2 + t][r] + b2r[t];
  }  // layers

  // ---- final: xq = LN(x)@wqf+bqf -> outb ; ctxp = ctxn@wcf+bcf -> kvb ----
  float bqfr[2], bcfr[2];
#pragma unroll
  for (int t = 0; t < 2; ++t) {
    const int n = (w2t + t) * 16 + nl;
    bqfr[t] = bqf[n];
    bcfr[t] = bcf[n];
  }
  load_b8(wsp + 24 * PANEL, Ba, nl, q8, w2t);
  load_b8(wsp + 25 * PANEL, Bb, nl, q8, w2t);
  ln_x(xr, sm.xn, sm.scratch, wave, nl, qm);
  mfma32v(sm.xn, Ba, acc4, nl, q8, true);
  mfma32v(sm.ctxn, Bb, acck, nl, q8, true);
  store32(sm.outb, acc4, bqfr, nl, qm, w2t);
  store32(sm.kvb, acck, bcfr, nl, qm, w2t);
  __syncthreads();
  {
    const int px = tid >> 3, sub = tid & 7;
    const int lr = (((px >> 3) >> 1) << 2) | ((px & 7) >> 1);
    const unsigned short* qrow = sm.outb + px * CBS;
#pragma unroll
    for (int which = 0; which < 2; ++which) {
      if (which == 1 && sub != 0) break;
      const int kk = (which == 0) ? sub : 8;
      const int pp = pp_of(lr, kk);
      const unsigned short* crow = sm.kvb + pp * CBS;
      float s = 0.f;
#pragma unroll
      for (int c8 = 0; c8 < 16; ++c8) {
        const u16x8 qa = *reinterpret_cast<const u16x8*>(qrow + c8 * 8);
        const u16x8 ca = *reinterpret_cast<const u16x8*>(crow + c8 * 8);
#pragma unroll
        for (int j = 0; j < 8; ++j) s += bf2f(qa[j]) * bf2f(ca[j]);
      }
      sm.scratch[MSC_ATT + px * 12 + kk] = s;
    }
  }
  __syncthreads();
  if (tid < 32) {
    const int px = tid;
    const int hu = hu0 + (px >> 3), wu = wu0 + (px & 7);
    float lg[9], mx = -1e30f;
#pragma unroll
    for (int kk = 0; kk < 9; ++kk) {
      lg[kk] = sm.scratch[MSC_ATT + px * 12 + kk] * 0.08838834764831845f;
      mx = fmaxf(mx, lg[kk]);
    }
    float sum = 0.f;
#pragma unroll
    for (int kk = 0; kk < 9; ++kk) { lg[kk] = __expf(lg[kk] - mx); sum += lg[kk]; }
    const float inv = 1.f / sum;
#pragma unroll
    for (int kk = 0; kk < 9; ++kk)
      out[((bz * 9 + kk) * HuC + hu) * WuC + wu] = lg[kk] * inv;
  }
}

}  // namespace

extern "C" void kernel_launch(void* const* d_in, const int* in_sizes, int n_in,
                              void* d_out, int out_size, void* d_ws, size_t ws_size,
                              hipStream_t stream) {
  const float* fm   = (const float*)d_in[0];
  const float* fmu  = (const float*)d_in[1];
  const float* nc_w = (const float*)d_in[2];
  const float* nc_b = (const float*)d_in[3];
  const float* wq   = (const float*)d_in[4];
  const float* bq   = (const float*)d_in[5];
  const float* wkv  = (const float*)d_in[6];
  const float* bkv  = (const float*)d_in[7];
  const float* wo   = (const float*)d_in[8];
  const float* bo   = (const float*)d_in[9];
  const float* w1   = (const float*)d_in[10];
  const float* b1   = (const float*)d_in[11];
  const float* w2   = (const float*)d_in[12];
  const float* b2   = (const float*)d_in[13];
  const float* wqf  = (const float*)d_in[14];
  const float* bqf  = (const float*)d_in[15];
  const float* wcf  = (const float*)d_in[16];
  const float* bcf  = (const float*)d_in[17];
  float* out = (float*)d_out;

  dim3 grid(24, 32, 2);  // 4x8-pixel tiles
  if (ws_size >= WS_NEEDED) {
    unsigned short* wsp = (unsigned short*)d_ws;
    float* wsb = (float*)((char*)d_ws + (size_t)N_PANELS * PANEL * 2);
    prep_weights<<<dim3(106), dim3(256), 0, stream>>>(
        nc_w, nc_b, wq, wkv, bkv, wo, w1, w2, wqf, wcf, wsp, wsb);
    fused_interp_mfma<<<grid, dim3(THREADS), 0, stream>>>(
        fm, fmu, bq, bo, b1, b2, bqf, bcf, wsp, wsb, out);
  } else {
    fused_interp_kernel<<<grid, dim3(THREADS), 0, stream>>>(
        fm, fmu, nc_w, nc_b, wq, bq, wkv, bkv, wo, bo, w1, b1, w2, b2,
        wqf, bqf, wcf, bcf, out);
  }
}